// Round 1
// baseline (2038.062 us; speedup 1.0000x reference)
//
#include <hip/hip_runtime.h>
#include <cstdint>
#include <cstddef>

// B=64 batches, 256 leaves, E=D=U=512.
// Outputs: h_new[64*512], c_new[64*512], leaf_h_new[64*256*512] concat flat.

__device__ __forceinline__ float sigmoidf_(float x) { return 1.0f / (1.0f + __expf(-x)); }

// ---------------- GEMM: C = epilogue(A[M,K] @ W[K,512]) ----------------
// MODE 0: relu -> C
// MODE 1: write-stage epilogue -> C (leaf_h_new)
template<int MODE>
__global__ __launch_bounds__(256)
void gemm128(const float* __restrict__ A, const float* __restrict__ W,
             float* __restrict__ C, int M, int K,
             const float* __restrict__ ctrl_h, const float* __restrict__ attn,
             const float* __restrict__ upd, const float* __restrict__ leaf)
{
  constexpr int N = 512;
  __shared__ float As[8][132];   // A^T tile, padded (528B row = 16B aligned)
  __shared__ float Bs[8][132];
  const int tid = threadIdx.x;
  const int bm = blockIdx.y * 128;
  const int bn = blockIdx.x * 128;
  const int ar = tid >> 1, ac = (tid & 1) * 4;   // A loader: 128 rows x 8 k
  const int br = tid >> 5, bc = (tid & 31) * 4;  // B loader: 8 rows x 128 cols
  const int tm = (tid >> 4) * 8;                 // 16x16 threads, 8x8 micro-tile
  const int tn = (tid & 15) * 8;
  float acc[8][8];
#pragma unroll
  for (int i = 0; i < 8; ++i)
#pragma unroll
    for (int j = 0; j < 8; ++j) acc[i][j] = 0.f;

  for (int k0 = 0; k0 < K; k0 += 8) {
    float4 av = make_float4(0.f, 0.f, 0.f, 0.f);
    if (bm + ar < M) av = *(const float4*)(A + (size_t)(bm + ar) * K + (k0 + ac));
    As[ac + 0][ar] = av.x; As[ac + 1][ar] = av.y;
    As[ac + 2][ar] = av.z; As[ac + 3][ar] = av.w;
    *(float4*)(&Bs[br][bc]) = *(const float4*)(W + (size_t)(k0 + br) * N + (bn + bc));
    __syncthreads();
#pragma unroll
    for (int kk = 0; kk < 8; ++kk) {
      float a0[8], b0[8];
      *(float4*)(&a0[0]) = *(const float4*)(&As[kk][tm]);
      *(float4*)(&a0[4]) = *(const float4*)(&As[kk][tm + 4]);
      *(float4*)(&b0[0]) = *(const float4*)(&Bs[kk][tn]);
      *(float4*)(&b0[4]) = *(const float4*)(&Bs[kk][tn + 4]);
#pragma unroll
      for (int i = 0; i < 8; ++i)
#pragma unroll
        for (int j = 0; j < 8; ++j)
          acc[i][j] = fmaf(a0[i], b0[j], acc[i][j]);
    }
    __syncthreads();
  }

  if (MODE == 0) {
#pragma unroll
    for (int i = 0; i < 8; ++i) {
      const int row = bm + tm + i;
      if (row < M) {
        float4 v0, v1;
        v0.x = fmaxf(acc[i][0], 0.f); v0.y = fmaxf(acc[i][1], 0.f);
        v0.z = fmaxf(acc[i][2], 0.f); v0.w = fmaxf(acc[i][3], 0.f);
        v1.x = fmaxf(acc[i][4], 0.f); v1.y = fmaxf(acc[i][5], 0.f);
        v1.z = fmaxf(acc[i][6], 0.f); v1.w = fmaxf(acc[i][7], 0.f);
        *(float4*)(C + (size_t)row * N + bn + tn)     = v0;
        *(float4*)(C + (size_t)row * N + bn + tn + 4) = v1;
      }
    }
  } else {
#pragma unroll
    for (int i = 0; i < 8; ++i) {
      const int row = bm + tm + i;          // M = 16384 here, always in range
      const int bidx = row >> 8;            // batch = row / 256
      const float a = attn[row];
      const float u = upd[row];
      float4 ch0 = *(const float4*)(ctrl_h + (size_t)bidx * 512 + bn + tn);
      float4 ch1 = *(const float4*)(ctrl_h + (size_t)bidx * 512 + bn + tn + 4);
      float4 lf0 = *(const float4*)(leaf + (size_t)row * 512 + bn + tn);
      float4 lf1 = *(const float4*)(leaf + (size_t)row * 512 + bn + tn + 4);
      float chv[8] = {ch0.x, ch0.y, ch0.z, ch0.w, ch1.x, ch1.y, ch1.z, ch1.w};
      float lfv[8] = {lf0.x, lf0.y, lf0.z, lf0.w, lf1.x, lf1.y, lf1.z, lf1.w};
      float res[8];
#pragma unroll
      for (int j = 0; j < 8; ++j) {
        float cand = sigmoidf_(acc[i][j] + chv[j]);
        float w = u * cand + (1.f - u) * lfv[j];
        res[j] = a * w + (1.f - a) * lfv[j];
      }
      *(float4*)(C + (size_t)row * 512 + bn + tn)     = make_float4(res[0], res[1], res[2], res[3]);
      *(float4*)(C + (size_t)row * 512 + bn + tn + 4) = make_float4(res[4], res[5], res[6], res[7]);
    }
  }
}

// ---------------- per-batch: search (attn), upd, tree_out, control biases ----------------
__global__ __launch_bounds__(256)
void search_kernel(const float* __restrict__ inputs, const float* __restrict__ h0,
                   const float* __restrict__ W_s, const float* __restrict__ W_T,
                   const float* __restrict__ W_h,
                   const float* __restrict__ leaf, const float* __restrict__ levels,
                   float* __restrict__ attn_out, float* __restrict__ upd_out,
                   float* __restrict__ tree_out, float* __restrict__ ctrl_h)
{
  const int b = blockIdx.x;
  const int tid = threadIdx.x;
  __shared__ float wsl[512], wsc[512], wTl[512], wTc[512], ctrl[512];
  __shared__ float attn_sh[256], newattn[256], part[256];
  __shared__ float scal[2];

  for (int i = tid; i < 512; i += 256) {
    wsl[i]  = W_s[i];
    wsc[i]  = W_s[512 + i];
    wTl[i]  = W_T[i];
    wTc[i]  = W_T[512 + i];
    ctrl[i] = h0[b * 512 + i];
  }
  __syncthreads();

  // s_c = ctrl . W_s[512:], ctrl_T = ctrl . W_T[512:]
  float p1 = 0.f, p2 = 0.f;
  for (int i = tid; i < 512; i += 256) { p1 += ctrl[i] * wsc[i]; p2 += ctrl[i] * wTc[i]; }
  part[tid] = p1; __syncthreads();
  for (int s = 128; s > 0; s >>= 1) { if (tid < s) part[tid] += part[tid + s]; __syncthreads(); }
  if (tid == 0) scal[0] = part[0];
  __syncthreads();
  part[tid] = p2; __syncthreads();
  for (int s = 128; s > 0; s >>= 1) { if (tid < s) part[tid] += part[tid + s]; __syncthreads(); }
  if (tid == 0) scal[1] = part[0];
  __syncthreads();
  const float s_c = scal[0], ctrl_T = scal[1];

  // ctrl_h[b,:] = ctrl @ W_h[512:,:]
  for (int c = tid; c < 512; c += 256) {
    float s = 0.f;
    for (int k = 0; k < 512; ++k) s += ctrl[k] * W_h[(size_t)(512 + k) * 512 + c];
    ctrl_h[b * 512 + c] = s;
  }

  // top-down attention
  if (tid == 0) attn_sh[0] = 1.f;
  __syncthreads();
  constexpr int lvl_off[9] = {0, 0, 4194304, 6291456, 7340032,
                              7864320, 8126464, 8257536, 8323072};
#pragma unroll
  for (int l = 8; l >= 1; --l) {
    const int m = 256 >> l;       // nodes at this level
    const int g = 256 / m;        // threads per node
    const int j = tid / g;
    const int ln = tid % g;
    const float* nh = levels + lvl_off[l] + ((size_t)b * m + j) * 512;
    float p = 0.f;
    for (int k = ln; k < 512; k += g) p += nh[k] * wsl[k];
    part[tid] = p;
    __syncthreads();
    if (tid < m) {
      float s = s_c;
      for (int q = 0; q < g; ++q) s += part[tid * g + q];
      float mr = sigmoidf_(s);
      float a = attn_sh[tid];
      newattn[2 * tid]     = a * (1.f - mr);
      newattn[2 * tid + 1] = a * mr;
    }
    __syncthreads();
    if (tid < 2 * m) attn_sh[tid] = newattn[tid];
    __syncthreads();
  }
  attn_out[b * 256 + tid] = attn_sh[tid];

  // upd[b,n] = sigmoid(leaf[b,n,:] . W_T[:512] + ctrl_T)
  {
    const int wv = tid >> 6, ln = tid & 63;
    for (int n = wv; n < 256; n += 4) {
      const float* lr = leaf + ((size_t)b * 256 + n) * 512;
      float p = 0.f;
      for (int k = ln; k < 512; k += 64) p += lr[k] * wTl[k];
#pragma unroll
      for (int off = 32; off > 0; off >>= 1) p += __shfl_down(p, off);
      if (ln == 0) upd_out[b * 256 + n] = sigmoidf_(p + ctrl_T);
    }
  }

  // tree_out[b,e] = sum_n attn[n] * inputs[b,n,e]
  for (int e = tid; e < 512; e += 256) {
    float s = 0.f;
    for (int n = 0; n < 256; ++n) s += attn_sh[n] * inputs[((size_t)b * 256 + n) * 512 + e];
    tree_out[b * 512 + e] = s;
  }
}

// ---------------- fused LSTM cell ----------------
__global__ __launch_bounds__(256)
void lstm_kernel(const float* __restrict__ tre, const float* __restrict__ h0,
                 const float* __restrict__ c0, const float* __restrict__ kern,
                 const float* __restrict__ rec, const float* __restrict__ bias,
                 float* __restrict__ out_h, float* __restrict__ out_c)
{
  const int tid = threadIdx.x;
  const int u = blockIdx.x * 256 + tid;   // unit col, gridDim.x = 2
  const int b0 = blockIdx.y * 4;          // 4 batches per block, gridDim.y = 16
  __shared__ float ts[4][512], hs[4][512];
  for (int i = tid; i < 4 * 512; i += 256) {
    int bb = i >> 9, k = i & 511;
    ts[bb][k] = tre[(b0 + bb) * 512 + k];
    hs[bb][k] = h0[(b0 + bb) * 512 + k];
  }
  __syncthreads();
  float acc[4][4]; // [gate i,f,g,o][batch]
#pragma unroll
  for (int g = 0; g < 4; ++g) {
    float bv = bias[g * 512 + u];
#pragma unroll
    for (int bb = 0; bb < 4; ++bb) acc[g][bb] = bv;
  }
  for (int k = 0; k < 512; ++k) {
    const float w0 = kern[(size_t)k * 2048 + u];
    const float w1 = kern[(size_t)k * 2048 + 512 + u];
    const float w2 = kern[(size_t)k * 2048 + 1024 + u];
    const float w3 = kern[(size_t)k * 2048 + 1536 + u];
    const float r0 = rec[(size_t)k * 2048 + u];
    const float r1 = rec[(size_t)k * 2048 + 512 + u];
    const float r2 = rec[(size_t)k * 2048 + 1024 + u];
    const float r3 = rec[(size_t)k * 2048 + 1536 + u];
#pragma unroll
    for (int bb = 0; bb < 4; ++bb) {
      const float t = ts[bb][k], h = hs[bb][k];
      acc[0][bb] += t * w0 + h * r0;
      acc[1][bb] += t * w1 + h * r1;
      acc[2][bb] += t * w2 + h * r2;
      acc[3][bb] += t * w3 + h * r3;
    }
  }
#pragma unroll
  for (int bb = 0; bb < 4; ++bb) {
    const float c = sigmoidf_(acc[1][bb]) * c0[(b0 + bb) * 512 + u]
                  + sigmoidf_(acc[0][bb]) * tanhf(acc[2][bb]);
    const float h = sigmoidf_(acc[3][bb]) * tanhf(c);
    out_h[(b0 + bb) * 512 + u] = h;
    out_c[(b0 + bb) * 512 + u] = c;
  }
}

extern "C" void kernel_launch(void* const* d_in, const int* in_sizes, int n_in,
                              void* d_out, int out_size, void* d_ws, size_t ws_size,
                              hipStream_t stream) {
  const float* inputs = (const float*)d_in[0];
  const float* h0     = (const float*)d_in[1];
  const float* c0     = (const float*)d_in[2];
  const float* W_t    = (const float*)d_in[3];
  const float* W_j    = (const float*)d_in[4];
  const float* W_s    = (const float*)d_in[5];
  const float* W_h    = (const float*)d_in[6];
  const float* W_T    = (const float*)d_in[7];
  const float* kern   = (const float*)d_in[8];
  const float* rec    = (const float*)d_in[9];
  const float* bias   = (const float*)d_in[10];
  float* out = (float*)d_out;
  float* ws  = (float*)d_ws;

  // workspace layout (floats)
  float* leaf   = ws;                  // 16384 x 512
  float* levels = ws + 8388608;        // levels 1..8, 8355840 floats
  float* attn   = ws + 16744448;       // 64 x 256
  float* upd    = ws + 16760832;       // 64 x 256
  float* tre    = ws + 16777216;       // 64 x 512
  float* ch     = ws + 16809984;       // 64 x 512
  // total: 16842752 floats = 64.25 MiB

  // 1) leaf_h = relu(inputs @ W_t)
  gemm128<0><<<dim3(4, 128), 256, 0, stream>>>(inputs, W_t, leaf, 16384, 512,
                                               nullptr, nullptr, nullptr, nullptr);
  // 2) join levels (pair concat == contiguous reinterpret [B*m, 1024])
  const int lvl_off_h[9] = {0, 0, 4194304, 6291456, 7340032,
                            7864320, 8126464, 8257536, 8323072};
  const float* Aptr = leaf;
  for (int l = 1; l <= 8; ++l) {
    const int m = 256 >> l;
    const int M = 64 * m;
    float* Cl = levels + lvl_off_h[l];
    gemm128<0><<<dim3(4, (M + 127) / 128), 256, 0, stream>>>(Aptr, W_j, Cl, M, 1024,
                                                             nullptr, nullptr, nullptr, nullptr);
    Aptr = Cl;
  }
  // 3) search / attn / upd / tree_out / control biases
  search_kernel<<<dim3(64), 256, 0, stream>>>(inputs, h0, W_s, W_T, W_h,
                                              leaf, levels, attn, upd, tre, ch);
  // 4) write stage: leaf_h_new -> d_out[65536:]
  gemm128<1><<<dim3(4, 128), 256, 0, stream>>>(leaf, W_h, out + 65536, 16384, 512,
                                               ch, attn, upd, leaf);
  // 5) LSTM: h_new -> d_out[0:32768], c_new -> d_out[32768:65536]
  lstm_kernel<<<dim3(2, 16), 256, 0, stream>>>(tre, h0, c0, kern, rec, bias,
                                               out, out + 32768);
}

// Round 2
// 699.907 us; speedup vs baseline: 2.9119x; 2.9119x over previous
//
#include <hip/hip_runtime.h>
#include <hip/hip_bf16.h>
#include <cstdint>
#include <cstddef>

// B=64, N=256 leaves, E=D=U=512.
// Outputs: h_new[64*512], c_new[64*512], leaf_h_new[64*256*512] concat flat fp32.

__device__ __forceinline__ float sigmoidf_(float x) { return 1.0f / (1.0f + __expf(-x)); }

typedef __attribute__((ext_vector_type(8))) short bf16x8;   // 8 bf16 in 4 VGPRs
typedef __attribute__((ext_vector_type(4))) float f32x4;

__device__ __forceinline__ void load_lds16(const void* g, void* l) {
  __builtin_amdgcn_global_load_lds((const __attribute__((address_space(1))) void*)g,
                                   (__attribute__((address_space(3))) void*)l, 16, 0, 0);
}

// ---------- fp32 -> bf16 elementwise convert ----------
__global__ __launch_bounds__(256)
void cvt_bf16(const float* __restrict__ x, __hip_bfloat16* __restrict__ y, int n) {
  int i = (blockIdx.x * 256 + threadIdx.x) * 4;
  if (i < n) {
    float4 v = *(const float4*)(x + i);
    y[i]     = __float2bfloat16(v.x);
    y[i + 1] = __float2bfloat16(v.y);
    y[i + 2] = __float2bfloat16(v.z);
    y[i + 3] = __float2bfloat16(v.w);
  }
}

// ---------- W[K,512] fp32 -> Wt[512,K] bf16 (n-major for MFMA B staging) ----------
__global__ __launch_bounds__(256)
void tconv(const float* __restrict__ W, __hip_bfloat16* __restrict__ Wt, int K) {
  __shared__ float sh[32][33];
  const int tx = threadIdx.x & 31, ty = threadIdx.x >> 5;  // 32x8
  const int k0 = blockIdx.x * 32, n0 = blockIdx.y * 32;
#pragma unroll
  for (int i = 0; i < 4; ++i) {
    int k = k0 + ty + i * 8;
    sh[ty + i * 8][tx] = W[(size_t)k * 512 + n0 + tx];
  }
  __syncthreads();
#pragma unroll
  for (int i = 0; i < 4; ++i) {
    int n = n0 + ty + i * 8;
    Wt[(size_t)n * K + k0 + tx] = __float2bfloat16(sh[tx][ty + i * 8]);
  }
}

// ---------- bf16 MFMA GEMM: C = epi(A[M,K] @ Bt^T), N=512 fixed ----------
// A row-major [M,K] bf16; Bt row-major [512,K] bf16 (i.e. B^T).
// MODE 0: relu -> bf16 Cb.   MODE 1: write-stage epilogue -> fp32 Cf.
template<int MODE>
__global__ __launch_bounds__(256)
void mfma_gemm(const __hip_bfloat16* __restrict__ A, const __hip_bfloat16* __restrict__ Bt,
               int M, int K,
               __hip_bfloat16* __restrict__ Cb, float* __restrict__ Cf,
               const float* __restrict__ ctrl_h, const float* __restrict__ attn,
               const float* __restrict__ upd, const __hip_bfloat16* __restrict__ leaf) {
  __shared__ __align__(16) __hip_bfloat16 Asm[128 * 32];
  __shared__ __align__(16) __hip_bfloat16 Bsm[128 * 32];
  const int tid = threadIdx.x;
  const int wave = tid >> 6, lane = tid & 63;
  const int bm = blockIdx.y * 128, bn = blockIdx.x * 128;
  const int wm = (wave >> 1) * 64, wn = (wave & 1) * 64;
  const int q = lane >> 4, lr = lane & 15;

  f32x4 acc[4][4] = {};

  // staging: chunk c = 16B = 8 bf16; chunk -> (row=c>>2, kchunk=c&3)
  const int c0 = wave * 128 + lane, c1 = c0 + 64;
  const size_t ga0 = (size_t)(bm + (c0 >> 2)) * K + (c0 & 3) * 8;
  const size_t ga1 = (size_t)(bm + (c1 >> 2)) * K + (c1 & 3) * 8;
  const size_t gb0 = (size_t)(bn + (c0 >> 2)) * K + (c0 & 3) * 8;
  const size_t gb1 = (size_t)(bn + (c1 >> 2)) * K + (c1 & 3) * 8;
  __hip_bfloat16* la0 = Asm + wave * 1024;        // lane-uniform LDS bases
  __hip_bfloat16* la1 = Asm + wave * 1024 + 512;
  __hip_bfloat16* lb0 = Bsm + wave * 1024;
  __hip_bfloat16* lb1 = Bsm + wave * 1024 + 512;

  for (int k0v = 0; k0v < K; k0v += 32) {
    load_lds16(A + ga0 + k0v, la0);
    load_lds16(A + ga1 + k0v, la1);
    load_lds16(Bt + gb0 + k0v, lb0);
    load_lds16(Bt + gb1 + k0v, lb1);
    __syncthreads();   // compiler emits vmcnt(0) drain before s_barrier
    bf16x8 af[4], bfr[4];
#pragma unroll
    for (int mt = 0; mt < 4; ++mt)
      af[mt] = *(const bf16x8*)(Asm + (wm + mt * 16 + lr) * 32 + q * 8);
#pragma unroll
    for (int nt = 0; nt < 4; ++nt)
      bfr[nt] = *(const bf16x8*)(Bsm + (wn + nt * 16 + lr) * 32 + q * 8);
#pragma unroll
    for (int mt = 0; mt < 4; ++mt)
#pragma unroll
      for (int nt = 0; nt < 4; ++nt)
        acc[mt][nt] = __builtin_amdgcn_mfma_f32_16x16x32_bf16(af[mt], bfr[nt], acc[mt][nt], 0, 0, 0);
    __syncthreads();
  }

  // C/D layout (m89-verified): col = lane&15, row = (lane>>4)*4 + reg
  if (MODE == 0) {
#pragma unroll
    for (int mt = 0; mt < 4; ++mt) {
      const int rbase = bm + wm + mt * 16 + q * 4;
#pragma unroll
      for (int nt = 0; nt < 4; ++nt) {
        const int col = bn + wn + nt * 16 + lr;
#pragma unroll
        for (int r = 0; r < 4; ++r) {
          const int row = rbase + r;
          if (row < M)
            Cb[(size_t)row * 512 + col] = __float2bfloat16(fmaxf(acc[mt][nt][r], 0.f));
        }
      }
    }
  } else {
#pragma unroll
    for (int mt = 0; mt < 4; ++mt) {
      const int rbase = bm + wm + mt * 16 + q * 4;
#pragma unroll
      for (int r = 0; r < 4; ++r) {
        const int row = rbase + r;       // M=16384 here, always in range
        const float a = attn[row];
        const float u = upd[row];
        const int bidx = row >> 8;
#pragma unroll
        for (int nt = 0; nt < 4; ++nt) {
          const int col = bn + wn + nt * 16 + lr;
          const float cand = sigmoidf_(acc[mt][nt][r] + ctrl_h[(size_t)bidx * 512 + col]);
          const float lf = __bfloat162float(leaf[(size_t)row * 512 + col]);
          const float w = u * cand + (1.f - u) * lf;
          Cf[(size_t)row * 512 + col] = a * w + (1.f - a) * lf;
        }
      }
    }
  }
}

// ---------- per-batch: search (attn), upd, tree_out, control biases ----------
__global__ __launch_bounds__(256)
void search_kernel(const float* __restrict__ inputs, const float* __restrict__ h0,
                   const float* __restrict__ W_s, const float* __restrict__ W_T,
                   const float* __restrict__ W_h,
                   const __hip_bfloat16* __restrict__ leaf,
                   const __hip_bfloat16* __restrict__ levels,
                   float* __restrict__ attn_out, float* __restrict__ upd_out,
                   float* __restrict__ tree_out, float* __restrict__ ctrl_h) {
  const int b = blockIdx.x;
  const int tid = threadIdx.x;
  __shared__ float wsl[512], wsc[512], wTl[512], wTc[512], ctrl[512];
  __shared__ float attn_sh[256], newattn[256], part[256];
  __shared__ float scal[2];

  for (int i = tid; i < 512; i += 256) {
    wsl[i]  = W_s[i];
    wsc[i]  = W_s[512 + i];
    wTl[i]  = W_T[i];
    wTc[i]  = W_T[512 + i];
    ctrl[i] = h0[b * 512 + i];
  }
  __syncthreads();

  float p1 = 0.f, p2 = 0.f;
  for (int i = tid; i < 512; i += 256) { p1 += ctrl[i] * wsc[i]; p2 += ctrl[i] * wTc[i]; }
  part[tid] = p1; __syncthreads();
  for (int s = 128; s > 0; s >>= 1) { if (tid < s) part[tid] += part[tid + s]; __syncthreads(); }
  if (tid == 0) scal[0] = part[0];
  __syncthreads();
  part[tid] = p2; __syncthreads();
  for (int s = 128; s > 0; s >>= 1) { if (tid < s) part[tid] += part[tid + s]; __syncthreads(); }
  if (tid == 0) scal[1] = part[0];
  __syncthreads();
  const float s_c = scal[0], ctrl_T = scal[1];

  // ctrl_h[b,:] = ctrl @ W_h[512:,:]  (fp32)
  for (int c = tid; c < 512; c += 256) {
    float s = 0.f;
    for (int k = 0; k < 512; ++k) s += ctrl[k] * W_h[(size_t)(512 + k) * 512 + c];
    ctrl_h[b * 512 + c] = s;
  }

  if (tid == 0) attn_sh[0] = 1.f;
  __syncthreads();
  constexpr int lvl_off[9] = {0, 0, 4194304, 6291456, 7340032,
                              7864320, 8126464, 8257536, 8323072};
#pragma unroll
  for (int l = 8; l >= 1; --l) {
    const int m = 256 >> l;
    const int g = 256 / m;
    const int j = tid / g;
    const int ln = tid % g;
    const __hip_bfloat16* nh = levels + lvl_off[l] + ((size_t)b * m + j) * 512;
    float p = 0.f;
    for (int k = ln; k < 512; k += g) p += __bfloat162float(nh[k]) * wsl[k];
    part[tid] = p;
    __syncthreads();
    if (tid < m) {
      float s = s_c;
      for (int qq = 0; qq < g; ++qq) s += part[tid * g + qq];
      float mr = sigmoidf_(s);
      float a = attn_sh[tid];
      newattn[2 * tid]     = a * (1.f - mr);
      newattn[2 * tid + 1] = a * mr;
    }
    __syncthreads();
    if (tid < 2 * m) attn_sh[tid] = newattn[tid];
    __syncthreads();
  }
  attn_out[b * 256 + tid] = attn_sh[tid];

  // upd[b,n] = sigmoid(leaf[b,n,:].W_T[:512] + ctrl_T)
  {
    const int wv = tid >> 6, ln = tid & 63;
    for (int n = wv; n < 256; n += 4) {
      const __hip_bfloat16* lrp = leaf + ((size_t)b * 256 + n) * 512;
      float p = 0.f;
      for (int k = ln; k < 512; k += 64) p += __bfloat162float(lrp[k]) * wTl[k];
#pragma unroll
      for (int off = 32; off > 0; off >>= 1) p += __shfl_down(p, off);
      if (ln == 0) upd_out[b * 256 + n] = sigmoidf_(p + ctrl_T);
    }
  }

  // tree_out[b,e] = sum_n attn[n] * inputs[b,n,e]   (fp32)
  for (int e = tid; e < 512; e += 256) {
    float s = 0.f;
    for (int n = 0; n < 256; ++n) s += attn_sh[n] * inputs[((size_t)b * 256 + n) * 512 + e];
    tree_out[b * 512 + e] = s;
  }
}

// ---------- LSTM as GEMM: Z[64,2048] = [tre|h0] @ [kern;rec] + bias ----------
__global__ __launch_bounds__(256)
void lstm_gemm(const float* __restrict__ tre, const float* __restrict__ h0,
               const float* __restrict__ kern, const float* __restrict__ rec,
               const float* __restrict__ bias, float* __restrict__ Z) {
  const int tid = threadIdx.x;
  const int col = blockIdx.x * 256 + tid;   // gridDim.x = 8
  const int b0 = blockIdx.y * 4;            // gridDim.y = 16
  __shared__ float ts[4][512], hs[4][512];
  for (int i = tid; i < 2048; i += 256) {
    int bb = i >> 9, k = i & 511;
    ts[bb][k] = tre[(b0 + bb) * 512 + k];
    hs[bb][k] = h0[(b0 + bb) * 512 + k];
  }
  __syncthreads();
  const float bv = bias[col];
  float a0 = bv, a1 = bv, a2 = bv, a3 = bv;
#pragma unroll 8
  for (int k = 0; k < 512; ++k) {
    const float w = kern[(size_t)k * 2048 + col];
    const float r = rec[(size_t)k * 2048 + col];
    a0 += ts[0][k] * w + hs[0][k] * r;
    a1 += ts[1][k] * w + hs[1][k] * r;
    a2 += ts[2][k] * w + hs[2][k] * r;
    a3 += ts[3][k] * w + hs[3][k] * r;
  }
  Z[(size_t)(b0 + 0) * 2048 + col] = a0;
  Z[(size_t)(b0 + 1) * 2048 + col] = a1;
  Z[(size_t)(b0 + 2) * 2048 + col] = a2;
  Z[(size_t)(b0 + 3) * 2048 + col] = a3;
}

__global__ __launch_bounds__(256)
void lstm_combine(const float* __restrict__ Z, const float* __restrict__ c0,
                  float* __restrict__ out_h, float* __restrict__ out_c) {
  const int i = blockIdx.x * 256 + threadIdx.x;   // 64*512 threads
  const int b = i >> 9, u = i & 511;
  const float zi = Z[(size_t)b * 2048 + u];
  const float zf = Z[(size_t)b * 2048 + 512 + u];
  const float zg = Z[(size_t)b * 2048 + 1024 + u];
  const float zo = Z[(size_t)b * 2048 + 1536 + u];
  const float c = sigmoidf_(zf) * c0[i] + sigmoidf_(zi) * tanhf(zg);
  out_h[i] = sigmoidf_(zo) * tanhf(c);
  out_c[i] = c;
}

extern "C" void kernel_launch(void* const* d_in, const int* in_sizes, int n_in,
                              void* d_out, int out_size, void* d_ws, size_t ws_size,
                              hipStream_t stream) {
  const float* inputs = (const float*)d_in[0];
  const float* h0     = (const float*)d_in[1];
  const float* c0     = (const float*)d_in[2];
  const float* W_t    = (const float*)d_in[3];
  const float* W_j    = (const float*)d_in[4];
  const float* W_s    = (const float*)d_in[5];
  const float* W_h    = (const float*)d_in[6];
  const float* W_T    = (const float*)d_in[7];
  const float* kern   = (const float*)d_in[8];
  const float* rec    = (const float*)d_in[9];
  const float* bias   = (const float*)d_in[10];
  float* out = (float*)d_out;

  // workspace layout (bytes)
  char* p = (char*)d_ws;
  __hip_bfloat16* in_bf     = (__hip_bfloat16*)p; p += 16777216;   // 16384x512
  __hip_bfloat16* leaf_bf   = (__hip_bfloat16*)p; p += 16777216;   // 16384x512
  __hip_bfloat16* levels_bf = (__hip_bfloat16*)p; p += 16842752;   // 16320x512 + 128-row pad
  __hip_bfloat16* Wt_t      = (__hip_bfloat16*)p; p += 524288;     // [512][512]
  __hip_bfloat16* Wt_j      = (__hip_bfloat16*)p; p += 1048576;    // [512][1024]
  __hip_bfloat16* Wt_h      = (__hip_bfloat16*)p; p += 524288;     // [512][512]
  float* attn = (float*)p; p += 65536;    // 64x256
  float* upd  = (float*)p; p += 65536;    // 64x256
  float* tre  = (float*)p; p += 131072;   // 64x512
  float* ch   = (float*)p; p += 131072;   // 64x512
  float* Z    = (float*)p; p += 524288;   // 64x2048

  // 1) converts / weight transposes
  cvt_bf16<<<8192, 256, 0, stream>>>(inputs, in_bf, 8388608);
  tconv<<<dim3(16, 16), 256, 0, stream>>>(W_t, Wt_t, 512);
  tconv<<<dim3(32, 16), 256, 0, stream>>>(W_j, Wt_j, 1024);
  tconv<<<dim3(16, 16), 256, 0, stream>>>(W_h, Wt_h, 512);  // leaf half of W_h

  // 2) leaf_h = relu(inputs @ W_t)  -> bf16
  mfma_gemm<0><<<dim3(4, 128), 256, 0, stream>>>(in_bf, Wt_t, 16384, 512,
                                                 leaf_bf, nullptr, nullptr, nullptr, nullptr, nullptr);
  // 3) join levels (pair concat == reinterpret rows as [M,1024])
  const int lvl_off_h[9] = {0, 0, 4194304, 6291456, 7340032,
                            7864320, 8126464, 8257536, 8323072};
  const __hip_bfloat16* Aptr = leaf_bf;
  for (int l = 1; l <= 8; ++l) {
    const int M = 64 * (256 >> l);
    __hip_bfloat16* Cl = levels_bf + lvl_off_h[l];
    const int gy = (M + 127) / 128;
    mfma_gemm<0><<<dim3(4, gy), 256, 0, stream>>>(Aptr, Wt_j, M, 1024,
                                                  Cl, nullptr, nullptr, nullptr, nullptr, nullptr);
    Aptr = Cl;
  }
  // 4) search / attn / upd / tree_out / ctrl bias
  search_kernel<<<dim3(64), 256, 0, stream>>>(inputs, h0, W_s, W_T, W_h,
                                              leaf_bf, levels_bf, attn, upd, tre, ch);
  // 5) write stage -> leaf_h_new (fp32) at out[65536:]
  mfma_gemm<1><<<dim3(4, 128), 256, 0, stream>>>(leaf_bf, Wt_h, 16384, 512,
                                                 nullptr, out + 65536, ch, attn, upd, leaf_bf);
  // 6) LSTM
  lstm_gemm<<<dim3(8, 16), 256, 0, stream>>>(tre, h0, kern, rec, bias, Z);
  lstm_combine<<<128, 256, 0, stream>>>(Z, c0, out, out + 32768);
}

// Round 3
// 477.494 us; speedup vs baseline: 4.2682x; 1.4658x over previous
//
#include <hip/hip_runtime.h>
#include <hip/hip_bf16.h>
#include <cstdint>
#include <cstddef>

// B=64, N=256 leaves, E=D=U=512.
// Outputs: h_new[64*512], c_new[64*512], leaf_h_new[64*256*512] concat flat fp32.

__device__ __forceinline__ float sigmoidf_(float x) { return 1.0f / (1.0f + __expf(-x)); }

typedef __attribute__((ext_vector_type(8))) short bf16x8;   // 8 bf16 in 4 VGPRs
typedef __attribute__((ext_vector_type(4))) float f32x4;

__device__ __forceinline__ void load_lds16(const void* g, void* l) {
  __builtin_amdgcn_global_load_lds((const __attribute__((address_space(1))) void*)g,
                                   (__attribute__((address_space(3))) void*)l, 16, 0, 0);
}

// ---------- fp32 -> bf16 elementwise convert ----------
__global__ __launch_bounds__(256)
void cvt_bf16(const float* __restrict__ x, __hip_bfloat16* __restrict__ y, int n) {
  int i = (blockIdx.x * 256 + threadIdx.x) * 4;
  if (i < n) {
    float4 v = *(const float4*)(x + i);
    y[i]     = __float2bfloat16(v.x);
    y[i + 1] = __float2bfloat16(v.y);
    y[i + 2] = __float2bfloat16(v.z);
    y[i + 3] = __float2bfloat16(v.w);
  }
}

// ---------- W[K,512] fp32 -> Wt[512,K] bf16 (n-major for MFMA B staging) ----------
__global__ __launch_bounds__(256)
void tconv(const float* __restrict__ W, __hip_bfloat16* __restrict__ Wt, int K) {
  __shared__ float sh[32][33];
  const int tx = threadIdx.x & 31, ty = threadIdx.x >> 5;  // 32x8
  const int k0 = blockIdx.x * 32, n0 = blockIdx.y * 32;
#pragma unroll
  for (int i = 0; i < 4; ++i) {
    int k = k0 + ty + i * 8;
    sh[ty + i * 8][tx] = W[(size_t)k * 512 + n0 + tx];
  }
  __syncthreads();
#pragma unroll
  for (int i = 0; i < 4; ++i) {
    int n = n0 + ty + i * 8;
    Wt[(size_t)n * K + k0 + tx] = __float2bfloat16(sh[tx][ty + i * 8]);
  }
}

// ---------- bf16 MFMA GEMM: C = epi(A[M,K] @ Bt^T), N=512 fixed ----------
// MODE 0: relu -> bf16 Cb.   MODE 1: write-stage epilogue -> fp32 Cf.
template<int MODE>
__global__ __launch_bounds__(256)
void mfma_gemm(const __hip_bfloat16* __restrict__ A, const __hip_bfloat16* __restrict__ Bt,
               int M, int K,
               __hip_bfloat16* __restrict__ Cb, float* __restrict__ Cf,
               const float* __restrict__ ctrl_h, const float* __restrict__ attn,
               const float* __restrict__ upd, const __hip_bfloat16* __restrict__ leaf) {
  __shared__ __align__(16) __hip_bfloat16 Asm[128 * 32];
  __shared__ __align__(16) __hip_bfloat16 Bsm[128 * 32];
  const int tid = threadIdx.x;
  const int wave = tid >> 6, lane = tid & 63;
  const int bm = blockIdx.y * 128, bn = blockIdx.x * 128;
  const int wm = (wave >> 1) * 64, wn = (wave & 1) * 64;
  const int q = lane >> 4, lr = lane & 15;

  f32x4 acc[4][4] = {};

  const int c0 = wave * 128 + lane, c1 = c0 + 64;
  const size_t ga0 = (size_t)(bm + (c0 >> 2)) * K + (c0 & 3) * 8;
  const size_t ga1 = (size_t)(bm + (c1 >> 2)) * K + (c1 & 3) * 8;
  const size_t gb0 = (size_t)(bn + (c0 >> 2)) * K + (c0 & 3) * 8;
  const size_t gb1 = (size_t)(bn + (c1 >> 2)) * K + (c1 & 3) * 8;
  __hip_bfloat16* la0 = Asm + wave * 1024;
  __hip_bfloat16* la1 = Asm + wave * 1024 + 512;
  __hip_bfloat16* lb0 = Bsm + wave * 1024;
  __hip_bfloat16* lb1 = Bsm + wave * 1024 + 512;

  for (int k0v = 0; k0v < K; k0v += 32) {
    load_lds16(A + ga0 + k0v, la0);
    load_lds16(A + ga1 + k0v, la1);
    load_lds16(Bt + gb0 + k0v, lb0);
    load_lds16(Bt + gb1 + k0v, lb1);
    __syncthreads();
    bf16x8 af[4], bfr[4];
#pragma unroll
    for (int mt = 0; mt < 4; ++mt)
      af[mt] = *(const bf16x8*)(Asm + (wm + mt * 16 + lr) * 32 + q * 8);
#pragma unroll
    for (int nt = 0; nt < 4; ++nt)
      bfr[nt] = *(const bf16x8*)(Bsm + (wn + nt * 16 + lr) * 32 + q * 8);
#pragma unroll
    for (int mt = 0; mt < 4; ++mt)
#pragma unroll
      for (int nt = 0; nt < 4; ++nt)
        acc[mt][nt] = __builtin_amdgcn_mfma_f32_16x16x32_bf16(af[mt], bfr[nt], acc[mt][nt], 0, 0, 0);
    __syncthreads();
  }

  // C/D layout: col = lane&15, row = (lane>>4)*4 + reg
  if (MODE == 0) {
#pragma unroll
    for (int mt = 0; mt < 4; ++mt) {
      const int rbase = bm + wm + mt * 16 + q * 4;
#pragma unroll
      for (int nt = 0; nt < 4; ++nt) {
        const int col = bn + wn + nt * 16 + lr;
#pragma unroll
        for (int r = 0; r < 4; ++r) {
          const int row = rbase + r;
          if (row < M)
            Cb[(size_t)row * 512 + col] = __float2bfloat16(fmaxf(acc[mt][nt][r], 0.f));
        }
      }
    }
  } else {
#pragma unroll
    for (int mt = 0; mt < 4; ++mt) {
      const int rbase = bm + wm + mt * 16 + q * 4;
#pragma unroll
      for (int r = 0; r < 4; ++r) {
        const int row = rbase + r;
        const float a = attn[row];
        const float u = upd[row];
        const int bidx = row >> 8;
#pragma unroll
        for (int nt = 0; nt < 4; ++nt) {
          const int col = bn + wn + nt * 16 + lr;
          const float cand = sigmoidf_(acc[mt][nt][r] + ctrl_h[(size_t)bidx * 512 + col]);
          const float lf = __bfloat162float(leaf[(size_t)row * 512 + col]);
          const float w = u * cand + (1.f - u) * lf;
          Cf[(size_t)row * 512 + col] = a * w + (1.f - a) * lf;
        }
      }
    }
  }
}

// ---------- ctrl_h split-K: chp[z][b][col] = sum_{k in slice z} h0[b,k]*W_h[512+k,col] ----------
__global__ __launch_bounds__(256)
void ctrl_gemm(const float* __restrict__ h0, const float* __restrict__ W_h,
               float* __restrict__ chp) {
  const int col = blockIdx.x * 256 + threadIdx.x;  // gridDim.x = 2
  const int b   = blockIdx.y;                      // 64
  const int z   = blockIdx.z;                      // 4 k-slices of 128
  __shared__ float hsh[128];
  if (threadIdx.x < 128) hsh[threadIdx.x] = h0[b * 512 + z * 128 + threadIdx.x];
  __syncthreads();
  const float* Wp = W_h + (size_t)(512 + z * 128) * 512 + col;
  float s = 0.f;
#pragma unroll 8
  for (int k = 0; k < 128; ++k) s += hsh[k] * Wp[(size_t)k * 512];
  chp[((size_t)z * 64 + b) * 512 + col] = s;
}

__global__ __launch_bounds__(256)
void ctrl_reduce(const float* __restrict__ chp, float* __restrict__ ch) {
  const int i = blockIdx.x * 256 + threadIdx.x;    // 32768 elems
  ch[i] = chp[i] + chp[32768 + i] + chp[65536 + i] + chp[98304 + i];
}

// ---------- per-batch: search (attn), upd, tree_out ----------
__global__ __launch_bounds__(256)
void search_kernel(const float* __restrict__ inputs, const float* __restrict__ h0,
                   const float* __restrict__ W_s, const float* __restrict__ W_T,
                   const __hip_bfloat16* __restrict__ leaf,
                   const __hip_bfloat16* __restrict__ levels,
                   float* __restrict__ attn_out, float* __restrict__ upd_out,
                   float* __restrict__ tree_out) {
  const int b = blockIdx.x;
  const int tid = threadIdx.x;
  __shared__ float wsl[512], wsc[512], wTl[512], wTc[512], ctrl[512];
  __shared__ float attn_sh[256], newattn[256], part[256];
  __shared__ float tpart[4][512];
  __shared__ float scal[2];

  for (int i = tid; i < 512; i += 256) {
    wsl[i]  = W_s[i];
    wsc[i]  = W_s[512 + i];
    wTl[i]  = W_T[i];
    wTc[i]  = W_T[512 + i];
    ctrl[i] = h0[b * 512 + i];
  }
  __syncthreads();

  float p1 = 0.f, p2 = 0.f;
  for (int i = tid; i < 512; i += 256) { p1 += ctrl[i] * wsc[i]; p2 += ctrl[i] * wTc[i]; }
  part[tid] = p1; __syncthreads();
  for (int s = 128; s > 0; s >>= 1) { if (tid < s) part[tid] += part[tid + s]; __syncthreads(); }
  if (tid == 0) scal[0] = part[0];
  __syncthreads();
  part[tid] = p2; __syncthreads();
  for (int s = 128; s > 0; s >>= 1) { if (tid < s) part[tid] += part[tid + s]; __syncthreads(); }
  if (tid == 0) scal[1] = part[0];
  __syncthreads();
  const float s_c = scal[0], ctrl_T = scal[1];

  if (tid == 0) attn_sh[0] = 1.f;
  __syncthreads();
  constexpr int lvl_off[9] = {0, 0, 4194304, 6291456, 7340032,
                              7864320, 8126464, 8257536, 8323072};
#pragma unroll
  for (int l = 8; l >= 1; --l) {
    const int m = 256 >> l;
    const int g = 256 / m;
    const int j = tid / g;
    const int ln = tid % g;
    const __hip_bfloat16* nh = levels + lvl_off[l] + ((size_t)b * m + j) * 512;
    float p = 0.f;
    for (int k = ln; k < 512; k += g) p += __bfloat162float(nh[k]) * wsl[k];
    part[tid] = p;
    __syncthreads();
    if (tid < m) {
      float s = s_c;
      for (int qq = 0; qq < g; ++qq) s += part[tid * g + qq];
      float mr = sigmoidf_(s);
      float a = attn_sh[tid];
      newattn[2 * tid]     = a * (1.f - mr);
      newattn[2 * tid + 1] = a * mr;
    }
    __syncthreads();
    if (tid < 2 * m) attn_sh[tid] = newattn[tid];
    __syncthreads();
  }
  attn_out[b * 256 + tid] = attn_sh[tid];

  // upd[b,n] = sigmoid(leaf[b,n,:].W_T[:512] + ctrl_T)
  {
    const int wv = tid >> 6, ln = tid & 63;
    for (int n = wv; n < 256; n += 4) {
      const __hip_bfloat16* lrp = leaf + ((size_t)b * 256 + n) * 512;
      float p = 0.f;
      for (int k = ln; k < 512; k += 64) p += __bfloat162float(lrp[k]) * wTl[k];
#pragma unroll
      for (int off = 32; off > 0; off >>= 1) p += __shfl_down(p, off);
      if (ln == 0) upd_out[b * 256 + n] = sigmoidf_(p + ctrl_T);
    }
  }
  __syncthreads();

  // tree_out[b,e] = sum_n attn[n]*inputs[b,n,e] — 4 waves over n-slices, LDS partials
  {
    const int wv = tid >> 6, ln = tid & 63;
    float s[8];
#pragma unroll
    for (int j = 0; j < 8; ++j) s[j] = 0.f;
    for (int nn = 0; nn < 64; ++nn) {
      const int n = wv * 64 + nn;
      const float a = attn_sh[n];
      const float* row = inputs + ((size_t)b * 256 + n) * 512;
#pragma unroll
      for (int j = 0; j < 8; ++j) s[j] += a * row[j * 64 + ln];
    }
#pragma unroll
    for (int j = 0; j < 8; ++j) tpart[wv][j * 64 + ln] = s[j];
    __syncthreads();
    for (int e = tid; e < 512; e += 256)
      tree_out[b * 512 + e] = tpart[0][e] + tpart[1][e] + tpart[2][e] + tpart[3][e];
  }
}

// ---------- LSTM split-K GEMM: Zp[z][b][col] partials ----------
__global__ __launch_bounds__(256)
void lstm_gemm_splitk(const float* __restrict__ tre, const float* __restrict__ h0,
                      const float* __restrict__ kern, const float* __restrict__ rec,
                      float* __restrict__ Zp) {
  const int tid = threadIdx.x;
  const int col = blockIdx.x * 256 + tid;   // gridDim.x = 8
  const int b0 = blockIdx.y * 4;            // gridDim.y = 16
  const int z = blockIdx.z;                 // gridDim.z = 8, slices of 128
  const float* X = (z < 4) ? tre : h0;
  const float* W = (z < 4) ? (kern + (size_t)z * 128 * 2048)
                           : (rec + (size_t)(z - 4) * 128 * 2048);
  const int koff = (z & 3) * 128;
  __shared__ float xs[4][128];
  for (int i = tid; i < 512; i += 256) {
    int bb = i >> 7, k = i & 127;
    xs[bb][k] = X[(b0 + bb) * 512 + koff + k];
  }
  __syncthreads();
  float a0 = 0.f, a1 = 0.f, a2 = 0.f, a3 = 0.f;
#pragma unroll 8
  for (int k = 0; k < 128; ++k) {
    const float w = W[(size_t)k * 2048 + col];
    a0 += xs[0][k] * w;
    a1 += xs[1][k] * w;
    a2 += xs[2][k] * w;
    a3 += xs[3][k] * w;
  }
  Zp[((size_t)z * 64 + b0 + 0) * 2048 + col] = a0;
  Zp[((size_t)z * 64 + b0 + 1) * 2048 + col] = a1;
  Zp[((size_t)z * 64 + b0 + 2) * 2048 + col] = a2;
  Zp[((size_t)z * 64 + b0 + 3) * 2048 + col] = a3;
}

__global__ __launch_bounds__(256)
void lstm_combine(const float* __restrict__ Zp, const float* __restrict__ bias,
                  const float* __restrict__ c0,
                  float* __restrict__ out_h, float* __restrict__ out_c) {
  const int i = blockIdx.x * 256 + threadIdx.x;   // 64*512 threads
  const int b = i >> 9, u = i & 511;
  float zi = bias[u], zf = bias[512 + u], zg = bias[1024 + u], zo = bias[1536 + u];
#pragma unroll
  for (int z = 0; z < 8; ++z) {
    const size_t base = ((size_t)z * 64 + b) * 2048;
    zi += Zp[base + u];
    zf += Zp[base + 512 + u];
    zg += Zp[base + 1024 + u];
    zo += Zp[base + 1536 + u];
  }
  const float c = sigmoidf_(zf) * c0[i] + sigmoidf_(zi) * tanhf(zg);
  out_h[i] = sigmoidf_(zo) * tanhf(c);
  out_c[i] = c;
}

extern "C" void kernel_launch(void* const* d_in, const int* in_sizes, int n_in,
                              void* d_out, int out_size, void* d_ws, size_t ws_size,
                              hipStream_t stream) {
  const float* inputs = (const float*)d_in[0];
  const float* h0     = (const float*)d_in[1];
  const float* c0     = (const float*)d_in[2];
  const float* W_t    = (const float*)d_in[3];
  const float* W_j    = (const float*)d_in[4];
  const float* W_s    = (const float*)d_in[5];
  const float* W_h    = (const float*)d_in[6];
  const float* W_T    = (const float*)d_in[7];
  const float* kern   = (const float*)d_in[8];
  const float* rec    = (const float*)d_in[9];
  const float* bias   = (const float*)d_in[10];
  float* out = (float*)d_out;

  // workspace layout (bytes)
  char* p = (char*)d_ws;
  __hip_bfloat16* in_bf     = (__hip_bfloat16*)p; p += 16777216;   // 16384x512
  __hip_bfloat16* leaf_bf   = (__hip_bfloat16*)p; p += 16777216;   // 16384x512
  __hip_bfloat16* levels_bf = (__hip_bfloat16*)p; p += 16842752;   // 16320x512 + pad
  __hip_bfloat16* Wt_t      = (__hip_bfloat16*)p; p += 524288;     // [512][512]
  __hip_bfloat16* Wt_j      = (__hip_bfloat16*)p; p += 1048576;    // [512][1024]
  __hip_bfloat16* Wt_h      = (__hip_bfloat16*)p; p += 524288;     // [512][512]
  float* attn = (float*)p; p += 65536;    // 64x256
  float* upd  = (float*)p; p += 65536;    // 64x256
  float* tre  = (float*)p; p += 131072;   // 64x512
  float* chp  = (float*)p; p += 524288;   // 4x64x512 partials
  float* ch   = (float*)p; p += 131072;   // 64x512
  float* Zp   = (float*)p; p += 4194304;  // 8x64x2048 partials

  // 1) converts / weight transposes / ctrl_h (independent of GEMM chain)
  cvt_bf16<<<8192, 256, 0, stream>>>(inputs, in_bf, 8388608);
  tconv<<<dim3(16, 16), 256, 0, stream>>>(W_t, Wt_t, 512);
  tconv<<<dim3(32, 16), 256, 0, stream>>>(W_j, Wt_j, 1024);
  tconv<<<dim3(16, 16), 256, 0, stream>>>(W_h, Wt_h, 512);
  ctrl_gemm<<<dim3(2, 64, 4), 256, 0, stream>>>(h0, W_h, chp);
  ctrl_reduce<<<128, 256, 0, stream>>>(chp, ch);

  // 2) leaf_h = relu(inputs @ W_t) -> bf16
  mfma_gemm<0><<<dim3(4, 128), 256, 0, stream>>>(in_bf, Wt_t, 16384, 512,
                                                 leaf_bf, nullptr, nullptr, nullptr, nullptr, nullptr);
  // 3) join levels (pair concat == reinterpret rows as [M,1024])
  const int lvl_off_h[9] = {0, 0, 4194304, 6291456, 7340032,
                            7864320, 8126464, 8257536, 8323072};
  const __hip_bfloat16* Aptr = leaf_bf;
  for (int l = 1; l <= 8; ++l) {
    const int M = 64 * (256 >> l);
    __hip_bfloat16* Cl = levels_bf + lvl_off_h[l];
    const int gy = (M + 127) / 128;
    mfma_gemm<0><<<dim3(4, gy), 256, 0, stream>>>(Aptr, Wt_j, M, 1024,
                                                  Cl, nullptr, nullptr, nullptr, nullptr, nullptr);
    Aptr = Cl;
  }
  // 4) search / attn / upd / tree_out
  search_kernel<<<dim3(64), 256, 0, stream>>>(inputs, h0, W_s, W_T,
                                              leaf_bf, levels_bf, attn, upd, tre);
  // 5) write stage -> leaf_h_new (fp32) at out[65536:]
  mfma_gemm<1><<<dim3(4, 128), 256, 0, stream>>>(leaf_bf, Wt_h, 16384, 512,
                                                 nullptr, out + 65536, ch, attn, upd, leaf_bf);
  // 6) LSTM
  lstm_gemm_splitk<<<dim3(8, 16, 8), 256, 0, stream>>>(tre, h0, kern, rec, Zp);
  lstm_combine<<<128, 256, 0, stream>>>(Zp, bias, c0, out, out + 32768);
}

// Round 4
// 425.438 us; speedup vs baseline: 4.7905x; 1.1224x over previous
//
#include <hip/hip_runtime.h>
#include <hip/hip_bf16.h>
#include <cstdint>
#include <cstddef>

// B=64, N=256 leaves, E=D=U=512.
// Outputs: h_new[64*512], c_new[64*512], leaf_h_new[64*256*512] concat flat fp32.

__device__ __forceinline__ float sigmoidf_(float x) { return 1.0f / (1.0f + __expf(-x)); }

typedef __attribute__((ext_vector_type(8))) short bf16x8;
typedef __attribute__((ext_vector_type(4))) float f32x4;

__device__ __forceinline__ void load_lds16(const void* g, void* l) {
  __builtin_amdgcn_global_load_lds((const __attribute__((address_space(1))) void*)g,
                                   (__attribute__((address_space(3))) void*)l, 16, 0, 0);
}

// level row offsets (elements/512) within the levels array
__constant__ size_t LVL_OFF_E[9] = {0, 0, 4194304, 6291456, 7340032,
                                    7864320, 8126464, 8257536, 8323072};

// ---------- fp32 -> bf16 ----------
__global__ __launch_bounds__(256)
void cvt_bf16(const float* __restrict__ x, __hip_bfloat16* __restrict__ y, int n) {
  int i = (blockIdx.x * 256 + threadIdx.x) * 4;
  if (i < n) {
    float4 v = *(const float4*)(x + i);
    y[i]     = __float2bfloat16(v.x);
    y[i + 1] = __float2bfloat16(v.y);
    y[i + 2] = __float2bfloat16(v.z);
    y[i + 3] = __float2bfloat16(v.w);
  }
}

// ---------- all three weight transposes in one launch ----------
__global__ __launch_bounds__(256)
void tconv_all(const float* __restrict__ W_t, const float* __restrict__ W_j,
               const float* __restrict__ W_h,
               __hip_bfloat16* __restrict__ Wt_t, __hip_bfloat16* __restrict__ Wt_j,
               __hip_bfloat16* __restrict__ Wt_h) {
  const int z = blockIdx.z;
  if (z != 1 && blockIdx.x >= 16) return;
  const int K = (z == 1) ? 1024 : 512;
  const float* W = (z == 0) ? W_t : ((z == 1) ? W_j : W_h);
  __hip_bfloat16* Wt = (z == 0) ? Wt_t : ((z == 1) ? Wt_j : Wt_h);
  __shared__ float sh[32][33];
  const int tx = threadIdx.x & 31, ty = threadIdx.x >> 5;
  const int k0 = blockIdx.x * 32, n0 = blockIdx.y * 32;
#pragma unroll
  for (int i = 0; i < 4; ++i)
    sh[ty + i * 8][tx] = W[(size_t)(k0 + ty + i * 8) * 512 + n0 + tx];
  __syncthreads();
#pragma unroll
  for (int i = 0; i < 4; ++i)
    Wt[(size_t)(n0 + ty + i * 8) * K + k0 + tx] = __float2bfloat16(sh[tx][ty + i * 8]);
}

// ---------- bf16 MFMA GEMM: C = epi(A[M,K] @ Bt^T), N=512 ----------
template<int MODE>
__global__ __launch_bounds__(256)
void mfma_gemm(const __hip_bfloat16* __restrict__ A, const __hip_bfloat16* __restrict__ Bt,
               int M, int K,
               __hip_bfloat16* __restrict__ Cb, float* __restrict__ Cf,
               const float* __restrict__ ctrl_h, const float* __restrict__ attn,
               const float* __restrict__ upd, const __hip_bfloat16* __restrict__ leaf) {
  __shared__ __align__(16) __hip_bfloat16 Asm[128 * 32];
  __shared__ __align__(16) __hip_bfloat16 Bsm[128 * 32];
  const int tid = threadIdx.x;
  const int wave = tid >> 6, lane = tid & 63;
  const int bm = blockIdx.y * 128, bn = blockIdx.x * 128;
  const int wm = (wave >> 1) * 64, wn = (wave & 1) * 64;
  const int q = lane >> 4, lr = lane & 15;

  f32x4 acc[4][4] = {};

  const int c0 = wave * 128 + lane, c1 = c0 + 64;
  const size_t ga0 = (size_t)(bm + (c0 >> 2)) * K + (c0 & 3) * 8;
  const size_t ga1 = (size_t)(bm + (c1 >> 2)) * K + (c1 & 3) * 8;
  const size_t gb0 = (size_t)(bn + (c0 >> 2)) * K + (c0 & 3) * 8;
  const size_t gb1 = (size_t)(bn + (c1 >> 2)) * K + (c1 & 3) * 8;
  __hip_bfloat16* la0 = Asm + wave * 1024;
  __hip_bfloat16* la1 = Asm + wave * 1024 + 512;
  __hip_bfloat16* lb0 = Bsm + wave * 1024;
  __hip_bfloat16* lb1 = Bsm + wave * 1024 + 512;

  for (int k0v = 0; k0v < K; k0v += 32) {
    load_lds16(A + ga0 + k0v, la0);
    load_lds16(A + ga1 + k0v, la1);
    load_lds16(Bt + gb0 + k0v, lb0);
    load_lds16(Bt + gb1 + k0v, lb1);
    __syncthreads();
    bf16x8 af[4], bfr[4];
#pragma unroll
    for (int mt = 0; mt < 4; ++mt)
      af[mt] = *(const bf16x8*)(Asm + (wm + mt * 16 + lr) * 32 + q * 8);
#pragma unroll
    for (int nt = 0; nt < 4; ++nt)
      bfr[nt] = *(const bf16x8*)(Bsm + (wn + nt * 16 + lr) * 32 + q * 8);
#pragma unroll
    for (int mt = 0; mt < 4; ++mt)
#pragma unroll
      for (int nt = 0; nt < 4; ++nt)
        acc[mt][nt] = __builtin_amdgcn_mfma_f32_16x16x32_bf16(af[mt], bfr[nt], acc[mt][nt], 0, 0, 0);
    __syncthreads();
  }

  if (MODE == 0) {
#pragma unroll
    for (int mt = 0; mt < 4; ++mt) {
      const int rbase = bm + wm + mt * 16 + q * 4;
#pragma unroll
      for (int nt = 0; nt < 4; ++nt) {
        const int col = bn + wn + nt * 16 + lr;
#pragma unroll
        for (int r = 0; r < 4; ++r) {
          const int row = rbase + r;
          if (row < M)
            Cb[(size_t)row * 512 + col] = __float2bfloat16(fmaxf(acc[mt][nt][r], 0.f));
        }
      }
    }
  } else {
#pragma unroll
    for (int mt = 0; mt < 4; ++mt) {
      const int rbase = bm + wm + mt * 16 + q * 4;
#pragma unroll
      for (int r = 0; r < 4; ++r) {
        const int row = rbase + r;
        const float a = attn[row];
        const float u = upd[row];
        const int bidx = row >> 8;
#pragma unroll
        for (int nt = 0; nt < 4; ++nt) {
          const int col = bn + wn + nt * 16 + lr;
          const float cand = sigmoidf_(acc[mt][nt][r] + ctrl_h[(size_t)bidx * 512 + col]);
          const float lf = __bfloat162float(leaf[(size_t)row * 512 + col]);
          const float w = u * cand + (1.f - u) * lf;
          Cf[(size_t)row * 512 + col] = a * w + (1.f - a) * lf;
        }
      }
    }
  }
}

// ---------- fused join levels 4..8, one block per batch ----------
__global__ __launch_bounds__(256)
void join_tail(const __hip_bfloat16* __restrict__ Wt_j,
               __hip_bfloat16* __restrict__ levels) {
  __shared__ __align__(16) __hip_bfloat16 buf0[32 * 512];
  __shared__ __align__(16) __hip_bfloat16 buf1[16 * 512];
  const int b = blockIdx.x;
  const int tid = threadIdx.x;
  const int wave = tid >> 6, lane = tid & 63;
  const int q = lane >> 4, lr = lane & 15;

  // load level 3 (32 rows x 512) for this batch into buf0
  {
    const __hip_bfloat16* src = levels + 6291456 + (size_t)b * 32 * 512;
#pragma unroll
    for (int i = 0; i < 8; ++i) {
      const int idx = tid + i * 256;
      *(bf16x8*)(buf0 + (size_t)idx * 8) = *(const bf16x8*)(src + (size_t)idx * 8);
    }
  }
  __syncthreads();

  const size_t off_e[9] = {0, 0, 4194304, 6291456, 7340032,
                           7864320, 8126464, 8257536, 8323072};
  __hip_bfloat16* cur = buf0;
  __hip_bfloat16* nxt = buf1;
  int m_out = 16;
  for (int l = 4; l <= 8; ++l, m_out >>= 1) {
#pragma unroll 2
    for (int j = 0; j < 8; ++j) {
      const int ntile = wave * 8 + j;
      const int arow = (lr < m_out) ? lr : 0;   // clamp padded rows in-bounds
      const __hip_bfloat16* ap = cur + (size_t)arow * 1024;
      const __hip_bfloat16* bp = Wt_j + (size_t)(ntile * 16 + lr) * 1024;
      f32x4 acc = {0.f, 0.f, 0.f, 0.f};
#pragma unroll 4
      for (int kk = 0; kk < 1024; kk += 32) {
        bf16x8 a = *(const bf16x8*)(ap + kk + q * 8);
        bf16x8 bb = *(const bf16x8*)(bp + kk + q * 8);
        acc = __builtin_amdgcn_mfma_f32_16x16x32_bf16(a, bb, acc, 0, 0, 0);
      }
      const int col = ntile * 16 + lr;
#pragma unroll
      for (int r = 0; r < 4; ++r) {
        const int row = q * 4 + r;
        if (row < m_out) {
          const __hip_bfloat16 bv = __float2bfloat16(fmaxf(acc[r], 0.f));
          nxt[(size_t)row * 512 + col] = bv;
          levels[off_e[l] + ((size_t)b * m_out + row) * 512 + col] = bv;
        }
      }
    }
    __syncthreads();
    __hip_bfloat16* t = cur; cur = nxt; nxt = t;
  }
}

// ---------- GEMV: y[row] = (sigmoid?)(X[row,:512].w + add[row>>8]) ----------
__global__ __launch_bounds__(256)
void gemv512(const __hip_bfloat16* __restrict__ X, const float* __restrict__ w,
             const float* __restrict__ addv, float* __restrict__ y,
             int apply_sig) {
  const int wave = threadIdx.x >> 6, lane = threadIdx.x & 63;
  const int row = blockIdx.x * 4 + wave;
  union { bf16x8 v; __hip_bfloat16 e[8]; } u;
  u.v = *(const bf16x8*)(X + (size_t)row * 512 + lane * 8);
  const float* wp = w + lane * 8;
  float p = 0.f;
#pragma unroll
  for (int j = 0; j < 8; ++j) p += __bfloat162float(u.e[j]) * wp[j];
#pragma unroll
  for (int off = 32; off > 0; off >>= 1) p += __shfl_down(p, off);
  if (lane == 0)
    y[row] = apply_sig ? sigmoidf_(p + addv[row >> 8]) : p;
}

// ---------- ctrl_T[b] = h0[b,:].W_T[512:] ----------
__global__ __launch_bounds__(256)
void prep_ctrl(const float* __restrict__ h0, const float* __restrict__ W_T,
               float* __restrict__ ctrlT) {
  const int b = blockIdx.x, tid = threadIdx.x;
  __shared__ float part[256];
  float p = 0.f;
  for (int i = tid; i < 512; i += 256) p += h0[b * 512 + i] * W_T[512 + i];
  part[tid] = p; __syncthreads();
  for (int s = 128; s > 0; s >>= 1) { if (tid < s) part[tid] += part[tid + s]; __syncthreads(); }
  if (tid == 0) ctrlT[b] = part[0];
}

// ---------- top-down attention from precomputed node scores ----------
__global__ __launch_bounds__(256)
void propagate(const float* __restrict__ sc, const float* __restrict__ h0,
               const float* __restrict__ W_s, float* __restrict__ attn_out) {
  const int b = blockIdx.x, tid = threadIdx.x;
  __shared__ float part[256], attn_sh[256], newattn[256];
  __shared__ float scs;
  float p = 0.f;
  for (int i = tid; i < 512; i += 256) p += h0[b * 512 + i] * W_s[512 + i];
  part[tid] = p; __syncthreads();
  for (int s = 128; s > 0; s >>= 1) { if (tid < s) part[tid] += part[tid + s]; __syncthreads(); }
  if (tid == 0) { scs = part[0]; attn_sh[0] = 1.f; }
  __syncthreads();
  const int row_off[9] = {0, 0, 8192, 12288, 14336, 15360, 15872, 16128, 16256};
#pragma unroll
  for (int l = 8; l >= 1; --l) {
    const int m = 256 >> l;
    if (tid < m) {
      const float mr = sigmoidf_(sc[row_off[l] + b * m + tid] + scs);
      const float a = attn_sh[tid];
      newattn[2 * tid]     = a * (1.f - mr);
      newattn[2 * tid + 1] = a * mr;
    }
    __syncthreads();
    if (tid < 2 * m) attn_sh[tid] = newattn[tid];
    __syncthreads();
  }
  attn_out[b * 256 + tid] = attn_sh[tid];
}

// ---------- tree_out partials over (n-slice, batch) ----------
__global__ __launch_bounds__(256)
void tree_part(const float* __restrict__ inputs, const float* __restrict__ attn,
               float* __restrict__ tp) {
  const int s = blockIdx.x, b = blockIdx.y;
  const int tid = threadIdx.x;
  __shared__ float a_sh[64];
  if (tid < 64) a_sh[tid] = attn[b * 256 + s * 64 + tid];
  __syncthreads();
  float acc0 = 0.f, acc1 = 0.f;
  const float* base = inputs + ((size_t)b * 256 + s * 64) * 512;
  for (int nn = 0; nn < 64; ++nn) {
    const float a = a_sh[nn];
    const float* row = base + (size_t)nn * 512;
    acc0 += a * row[tid];
    acc1 += a * row[tid + 256];
  }
  tp[((size_t)s * 64 + b) * 512 + tid]       = acc0;
  tp[((size_t)s * 64 + b) * 512 + tid + 256] = acc1;
}

__global__ __launch_bounds__(256)
void tree_reduce(const float* __restrict__ tp, float* __restrict__ tre) {
  const int i = blockIdx.x * 256 + threadIdx.x;   // 32768
  tre[i] = tp[i] + tp[32768 + i] + tp[65536 + i] + tp[98304 + i];
}

// ---------- ctrl_h split-K ----------
__global__ __launch_bounds__(256)
void ctrl_gemm(const float* __restrict__ h0, const float* __restrict__ W_h,
               float* __restrict__ chp) {
  const int col = blockIdx.x * 256 + threadIdx.x;
  const int b   = blockIdx.y;
  const int z   = blockIdx.z;
  __shared__ float hsh[128];
  if (threadIdx.x < 128) hsh[threadIdx.x] = h0[b * 512 + z * 128 + threadIdx.x];
  __syncthreads();
  const float* Wp = W_h + (size_t)(512 + z * 128) * 512 + col;
  float s = 0.f;
#pragma unroll 8
  for (int k = 0; k < 128; ++k) s += hsh[k] * Wp[(size_t)k * 512];
  chp[((size_t)z * 64 + b) * 512 + col] = s;
}

__global__ __launch_bounds__(256)
void ctrl_reduce(const float* __restrict__ chp, float* __restrict__ ch) {
  const int i = blockIdx.x * 256 + threadIdx.x;
  ch[i] = chp[i] + chp[32768 + i] + chp[65536 + i] + chp[98304 + i];
}

// ---------- LSTM split-K ----------
__global__ __launch_bounds__(256)
void lstm_gemm_splitk(const float* __restrict__ tre, const float* __restrict__ h0,
                      const float* __restrict__ kern, const float* __restrict__ rec,
                      float* __restrict__ Zp) {
  const int tid = threadIdx.x;
  const int col = blockIdx.x * 256 + tid;
  const int b0 = blockIdx.y * 4;
  const int z = blockIdx.z;
  const float* X = (z < 4) ? tre : h0;
  const float* W = (z < 4) ? (kern + (size_t)z * 128 * 2048)
                           : (rec + (size_t)(z - 4) * 128 * 2048);
  const int koff = (z & 3) * 128;
  __shared__ float xs[4][128];
  for (int i = tid; i < 512; i += 256) {
    int bb = i >> 7, k = i & 127;
    xs[bb][k] = X[(b0 + bb) * 512 + koff + k];
  }
  __syncthreads();
  float a0 = 0.f, a1 = 0.f, a2 = 0.f, a3 = 0.f;
#pragma unroll 8
  for (int k = 0; k < 128; ++k) {
    const float w = W[(size_t)k * 2048 + col];
    a0 += xs[0][k] * w;
    a1 += xs[1][k] * w;
    a2 += xs[2][k] * w;
    a3 += xs[3][k] * w;
  }
  Zp[((size_t)z * 64 + b0 + 0) * 2048 + col] = a0;
  Zp[((size_t)z * 64 + b0 + 1) * 2048 + col] = a1;
  Zp[((size_t)z * 64 + b0 + 2) * 2048 + col] = a2;
  Zp[((size_t)z * 64 + b0 + 3) * 2048 + col] = a3;
}

__global__ __launch_bounds__(256)
void lstm_combine(const float* __restrict__ Zp, const float* __restrict__ bias,
                  const float* __restrict__ c0,
                  float* __restrict__ out_h, float* __restrict__ out_c) {
  const int i = blockIdx.x * 256 + threadIdx.x;
  const int b = i >> 9, u = i & 511;
  float zi = bias[u], zf = bias[512 + u], zg = bias[1024 + u], zo = bias[1536 + u];
#pragma unroll
  for (int z = 0; z < 8; ++z) {
    const size_t base = ((size_t)z * 64 + b) * 2048;
    zi += Zp[base + u];
    zf += Zp[base + 512 + u];
    zg += Zp[base + 1024 + u];
    zo += Zp[base + 1536 + u];
  }
  const float c = sigmoidf_(zf) * c0[i] + sigmoidf_(zi) * tanhf(zg);
  out_h[i] = sigmoidf_(zo) * tanhf(c);
  out_c[i] = c;
}

extern "C" void kernel_launch(void* const* d_in, const int* in_sizes, int n_in,
                              void* d_out, int out_size, void* d_ws, size_t ws_size,
                              hipStream_t stream) {
  const float* inputs = (const float*)d_in[0];
  const float* h0     = (const float*)d_in[1];
  const float* c0     = (const float*)d_in[2];
  const float* W_t    = (const float*)d_in[3];
  const float* W_j    = (const float*)d_in[4];
  const float* W_s    = (const float*)d_in[5];
  const float* W_h    = (const float*)d_in[6];
  const float* W_T    = (const float*)d_in[7];
  const float* kern   = (const float*)d_in[8];
  const float* rec    = (const float*)d_in[9];
  const float* bias   = (const float*)d_in[10];
  float* out = (float*)d_out;

  char* p = (char*)d_ws;
  __hip_bfloat16* in_bf     = (__hip_bfloat16*)p; p += 16777216;   // 16384x512
  __hip_bfloat16* leaf_bf   = (__hip_bfloat16*)p; p += 16777216;   // 16384x512
  __hip_bfloat16* levels_bf = (__hip_bfloat16*)p; p += 16842752;   // 16320x512 + pad
  __hip_bfloat16* Wt_t      = (__hip_bfloat16*)p; p += 524288;
  __hip_bfloat16* Wt_j      = (__hip_bfloat16*)p; p += 1048576;
  __hip_bfloat16* Wt_h      = (__hip_bfloat16*)p; p += 524288;
  float* attn  = (float*)p; p += 65536;    // 64x256
  float* upd   = (float*)p; p += 65536;    // 64x256
  float* tre   = (float*)p; p += 131072;   // 64x512
  float* chp   = (float*)p; p += 524288;   // 4x64x512
  float* ch    = (float*)p; p += 131072;   // 64x512
  float* Zp    = (float*)p; p += 4194304;  // 8x64x2048
  float* sc    = (float*)p; p += 65536;    // 16320 node scores (+pad)
  float* ctrlT = (float*)p; p += 4096;     // 64
  float* tp    = (float*)p; p += 524288;   // 4x64x512 tree partials

  // prep (independent)
  cvt_bf16<<<8192, 256, 0, stream>>>(inputs, in_bf, 8388608);
  tconv_all<<<dim3(32, 16, 3), 256, 0, stream>>>(W_t, W_j, W_h, Wt_t, Wt_j, Wt_h);
  ctrl_gemm<<<dim3(2, 64, 4), 256, 0, stream>>>(h0, W_h, chp);
  ctrl_reduce<<<128, 256, 0, stream>>>(chp, ch);
  prep_ctrl<<<64, 256, 0, stream>>>(h0, W_T, ctrlT);

  // leaf embed
  mfma_gemm<0><<<dim3(4, 128), 256, 0, stream>>>(in_bf, Wt_t, 16384, 512,
                                                 leaf_bf, nullptr, nullptr, nullptr, nullptr, nullptr);
  // upd GEMV (needs leaf only)
  gemv512<<<4096, 256, 0, stream>>>(leaf_bf, W_T, ctrlT, upd, 1);

  // join levels 1..3 as tiled MFMA GEMMs
  const int lvl_off_h[9] = {0, 0, 4194304, 6291456, 7340032,
                            7864320, 8126464, 8257536, 8323072};
  const __hip_bfloat16* Aptr = leaf_bf;
  for (int l = 1; l <= 3; ++l) {
    const int M = 64 * (256 >> l);
    __hip_bfloat16* Cl = levels_bf + lvl_off_h[l];
    mfma_gemm<0><<<dim3(4, M / 128), 256, 0, stream>>>(Aptr, Wt_j, M, 1024,
                                                       Cl, nullptr, nullptr, nullptr, nullptr, nullptr);
    Aptr = Cl;
  }
  // levels 4..8 fused per-batch
  join_tail<<<64, 256, 0, stream>>>(Wt_j, levels_bf);

  // node scores GEMV over all 16320 level rows, then top-down attn
  gemv512<<<4080, 256, 0, stream>>>(levels_bf, W_s, nullptr, sc, 0);
  propagate<<<64, 256, 0, stream>>>(sc, h0, W_s, attn);

  // tree_out
  tree_part<<<dim3(4, 64), 256, 0, stream>>>(inputs, attn, tp);
  tree_reduce<<<128, 256, 0, stream>>>(tp, tre);

  // write stage -> leaf_h_new (fp32) at out[65536:]
  mfma_gemm<1><<<dim3(4, 128), 256, 0, stream>>>(leaf_bf, Wt_h, 16384, 512,
                                                 nullptr, out + 65536, ch, attn, upd, leaf_bf);
  // LSTM
  lstm_gemm_splitk<<<dim3(8, 16, 8), 256, 0, stream>>>(tre, h0, kern, rec, Zp);
  lstm_combine<<<128, 256, 0, stream>>>(Zp, bias, c0, out, out + 32768);
}

// Round 5
// 345.126 us; speedup vs baseline: 5.9053x; 1.2327x over previous
//
#include <hip/hip_runtime.h>
#include <hip/hip_bf16.h>
#include <cstdint>
#include <cstddef>

// B=64, N=256 leaves, E=D=U=512.
// Outputs: h_new[64*512], c_new[64*512], leaf_h_new[64*256*512] concat flat fp32.

__device__ __forceinline__ float sigmoidf_(float x) { return 1.0f / (1.0f + __expf(-x)); }

typedef __attribute__((ext_vector_type(8))) short bf16x8;
typedef __attribute__((ext_vector_type(4))) float f32x4;

__device__ __forceinline__ void load_lds16(const void* g, void* l) {
  __builtin_amdgcn_global_load_lds((const __attribute__((address_space(1))) void*)g,
                                   (__attribute__((address_space(3))) void*)l, 16, 0, 0);
}

// ---------- fp32 -> bf16 ----------
__global__ __launch_bounds__(256)
void cvt_bf16(const float* __restrict__ x, __hip_bfloat16* __restrict__ y, int n) {
  int i = (blockIdx.x * 256 + threadIdx.x) * 4;
  if (i < n) {
    float4 v = *(const float4*)(x + i);
    y[i]     = __float2bfloat16(v.x);
    y[i + 1] = __float2bfloat16(v.y);
    y[i + 2] = __float2bfloat16(v.z);
    y[i + 3] = __float2bfloat16(v.w);
  }
}

// ---------- all three weight transposes in one launch ----------
__global__ __launch_bounds__(256)
void tconv_all(const float* __restrict__ W_t, const float* __restrict__ W_j,
               const float* __restrict__ W_h,
               __hip_bfloat16* __restrict__ Wt_t, __hip_bfloat16* __restrict__ Wt_j,
               __hip_bfloat16* __restrict__ Wt_h) {
  const int z = blockIdx.z;
  if (z != 1 && blockIdx.x >= 16) return;
  const int K = (z == 1) ? 1024 : 512;
  const float* W = (z == 0) ? W_t : ((z == 1) ? W_j : W_h);
  __hip_bfloat16* Wt = (z == 0) ? Wt_t : ((z == 1) ? Wt_j : Wt_h);
  __shared__ float sh[32][33];
  const int tx = threadIdx.x & 31, ty = threadIdx.x >> 5;
  const int k0 = blockIdx.x * 32, n0 = blockIdx.y * 32;
#pragma unroll
  for (int i = 0; i < 4; ++i)
    sh[ty + i * 8][tx] = W[(size_t)(k0 + ty + i * 8) * 512 + n0 + tx];
  __syncthreads();
#pragma unroll
  for (int i = 0; i < 4; ++i)
    Wt[(size_t)(n0 + ty + i * 8) * K + k0 + tx] = __float2bfloat16(sh[tx][ty + i * 8]);
}

// ---------- bf16 MFMA GEMM: C = epi(A[M,K] @ Bt^T), N=512 ----------
template<int MODE>
__global__ __launch_bounds__(256)
void mfma_gemm(const __hip_bfloat16* __restrict__ A, const __hip_bfloat16* __restrict__ Bt,
               int M, int K,
               __hip_bfloat16* __restrict__ Cb, float* __restrict__ Cf,
               const float* __restrict__ ctrl_h, const float* __restrict__ attn,
               const float* __restrict__ upd, const __hip_bfloat16* __restrict__ leaf) {
  __shared__ __align__(16) __hip_bfloat16 Asm[128 * 32];
  __shared__ __align__(16) __hip_bfloat16 Bsm[128 * 32];
  const int tid = threadIdx.x;
  const int wave = tid >> 6, lane = tid & 63;
  const int bm = blockIdx.y * 128, bn = blockIdx.x * 128;
  const int wm = (wave >> 1) * 64, wn = (wave & 1) * 64;
  const int q = lane >> 4, lr = lane & 15;

  f32x4 acc[4][4] = {};

  const int c0 = wave * 128 + lane, c1 = c0 + 64;
  const size_t ga0 = (size_t)(bm + (c0 >> 2)) * K + (c0 & 3) * 8;
  const size_t ga1 = (size_t)(bm + (c1 >> 2)) * K + (c1 & 3) * 8;
  const size_t gb0 = (size_t)(bn + (c0 >> 2)) * K + (c0 & 3) * 8;
  const size_t gb1 = (size_t)(bn + (c1 >> 2)) * K + (c1 & 3) * 8;
  __hip_bfloat16* la0 = Asm + wave * 1024;
  __hip_bfloat16* la1 = Asm + wave * 1024 + 512;
  __hip_bfloat16* lb0 = Bsm + wave * 1024;
  __hip_bfloat16* lb1 = Bsm + wave * 1024 + 512;

  for (int k0v = 0; k0v < K; k0v += 32) {
    load_lds16(A + ga0 + k0v, la0);
    load_lds16(A + ga1 + k0v, la1);
    load_lds16(Bt + gb0 + k0v, lb0);
    load_lds16(Bt + gb1 + k0v, lb1);
    __syncthreads();
    bf16x8 af[4], bfr[4];
#pragma unroll
    for (int mt = 0; mt < 4; ++mt)
      af[mt] = *(const bf16x8*)(Asm + (wm + mt * 16 + lr) * 32 + q * 8);
#pragma unroll
    for (int nt = 0; nt < 4; ++nt)
      bfr[nt] = *(const bf16x8*)(Bsm + (wn + nt * 16 + lr) * 32 + q * 8);
#pragma unroll
    for (int mt = 0; mt < 4; ++mt)
#pragma unroll
      for (int nt = 0; nt < 4; ++nt)
        acc[mt][nt] = __builtin_amdgcn_mfma_f32_16x16x32_bf16(af[mt], bfr[nt], acc[mt][nt], 0, 0, 0);
    __syncthreads();
  }

  if (MODE == 0) {
#pragma unroll
    for (int mt = 0; mt < 4; ++mt) {
      const int rbase = bm + wm + mt * 16 + q * 4;
#pragma unroll
      for (int nt = 0; nt < 4; ++nt) {
        const int col = bn + wn + nt * 16 + lr;
#pragma unroll
        for (int r = 0; r < 4; ++r) {
          const int row = rbase + r;
          if (row < M)
            Cb[(size_t)row * 512 + col] = __float2bfloat16(fmaxf(acc[mt][nt][r], 0.f));
        }
      }
    }
  } else {
#pragma unroll
    for (int mt = 0; mt < 4; ++mt) {
      const int rbase = bm + wm + mt * 16 + q * 4;
#pragma unroll
      for (int r = 0; r < 4; ++r) {
        const int row = rbase + r;
        const float a = attn[row];
        const float u = upd[row];
        const int bidx = row >> 8;
#pragma unroll
        for (int nt = 0; nt < 4; ++nt) {
          const int col = bn + wn + nt * 16 + lr;
          const float cand = sigmoidf_(acc[mt][nt][r] + ctrl_h[(size_t)bidx * 512 + col]);
          const float lf = __bfloat162float(leaf[(size_t)row * 512 + col]);
          const float w = u * cand + (1.f - u) * lf;
          Cf[(size_t)row * 512 + col] = a * w + (1.f - a) * lf;
        }
      }
    }
  }
}

// ---------- tail join level: one 16x16 tile per wave, no LDS ----------
// in: prev level [64*m_in, 512] bf16 (m_in = 2*m_out, rows contiguous per batch
// so concat(h[2r],h[2r+1]) is 1024 contiguous bf16). out: [64*m_out, 512].
__global__ __launch_bounds__(256)
void join_level(const __hip_bfloat16* __restrict__ in, __hip_bfloat16* __restrict__ outp,
                const __hip_bfloat16* __restrict__ Wt_j, int m_out) {
  const int wave = threadIdx.x >> 6, lane = threadIdx.x & 63;
  const int q = lane >> 4, lr = lane & 15;
  const int ntile = blockIdx.x * 4 + wave;   // 0..31
  const int b = blockIdx.y;                  // 0..63
  const int arow = (lr < m_out) ? lr : (m_out - 1);  // clamp padded rows
  const __hip_bfloat16* ap = in + ((size_t)b * (2 * m_out) + 2 * arow) * 512 + q * 8;
  const __hip_bfloat16* bp = Wt_j + (size_t)(ntile * 16 + lr) * 1024 + q * 8;
  f32x4 acc = {0.f, 0.f, 0.f, 0.f};
#pragma unroll 8
  for (int k0 = 0; k0 < 1024; k0 += 32) {
    bf16x8 a  = *(const bf16x8*)(ap + k0);
    bf16x8 bb = *(const bf16x8*)(bp + k0);
    acc = __builtin_amdgcn_mfma_f32_16x16x32_bf16(a, bb, acc, 0, 0, 0);
  }
  const int col = ntile * 16 + lr;
#pragma unroll
  for (int r = 0; r < 4; ++r) {
    const int row = q * 4 + r;
    if (row < m_out)
      outp[((size_t)b * m_out + row) * 512 + col] = __float2bfloat16(fmaxf(acc[r], 0.f));
  }
}

// ---------- GEMV: y[row] = (sigmoid?)(X[row,:512].w + add[row>>8]) ----------
__global__ __launch_bounds__(256)
void gemv512(const __hip_bfloat16* __restrict__ X, const float* __restrict__ w,
             const float* __restrict__ addv, float* __restrict__ y,
             int apply_sig) {
  const int wave = threadIdx.x >> 6, lane = threadIdx.x & 63;
  const int row = blockIdx.x * 4 + wave;
  union { bf16x8 v; __hip_bfloat16 e[8]; } u;
  u.v = *(const bf16x8*)(X + (size_t)row * 512 + lane * 8);
  const float* wp = w + lane * 8;
  float p = 0.f;
#pragma unroll
  for (int j = 0; j < 8; ++j) p += __bfloat162float(u.e[j]) * wp[j];
#pragma unroll
  for (int off = 32; off > 0; off >>= 1) p += __shfl_down(p, off);
  if (lane == 0)
    y[row] = apply_sig ? sigmoidf_(p + addv[row >> 8]) : p;
}

// ---------- ctrl_T[b] = h0[b,:].W_T[512:] ----------
__global__ __launch_bounds__(256)
void prep_ctrl(const float* __restrict__ h0, const float* __restrict__ W_T,
               float* __restrict__ ctrlT) {
  const int b = blockIdx.x, tid = threadIdx.x;
  __shared__ float part[256];
  float p = 0.f;
  for (int i = tid; i < 512; i += 256) p += h0[b * 512 + i] * W_T[512 + i];
  part[tid] = p; __syncthreads();
  for (int s = 128; s > 0; s >>= 1) { if (tid < s) part[tid] += part[tid + s]; __syncthreads(); }
  if (tid == 0) ctrlT[b] = part[0];
}

// ---------- top-down attention from precomputed node scores ----------
__global__ __launch_bounds__(256)
void propagate(const float* __restrict__ sc, const float* __restrict__ h0,
               const float* __restrict__ W_s, float* __restrict__ attn_out) {
  const int b = blockIdx.x, tid = threadIdx.x;
  __shared__ float part[256], attn_sh[256], newattn[256];
  __shared__ float scs;
  float p = 0.f;
  for (int i = tid; i < 512; i += 256) p += h0[b * 512 + i] * W_s[512 + i];
  part[tid] = p; __syncthreads();
  for (int s = 128; s > 0; s >>= 1) { if (tid < s) part[tid] += part[tid + s]; __syncthreads(); }
  if (tid == 0) { scs = part[0]; attn_sh[0] = 1.f; }
  __syncthreads();
  const int row_off[9] = {0, 0, 8192, 12288, 14336, 15360, 15872, 16128, 16256};
#pragma unroll
  for (int l = 8; l >= 1; --l) {
    const int m = 256 >> l;
    if (tid < m) {
      const float mr = sigmoidf_(sc[row_off[l] + b * m + tid] + scs);
      const float a = attn_sh[tid];
      newattn[2 * tid]     = a * (1.f - mr);
      newattn[2 * tid + 1] = a * mr;
    }
    __syncthreads();
    if (tid < 2 * m) attn_sh[tid] = newattn[tid];
    __syncthreads();
  }
  attn_out[b * 256 + tid] = attn_sh[tid];
}

// ---------- tree_out partials over (n-slice, batch) ----------
__global__ __launch_bounds__(256)
void tree_part(const float* __restrict__ inputs, const float* __restrict__ attn,
               float* __restrict__ tp) {
  const int s = blockIdx.x, b = blockIdx.y;
  const int tid = threadIdx.x;
  __shared__ float a_sh[64];
  if (tid < 64) a_sh[tid] = attn[b * 256 + s * 64 + tid];
  __syncthreads();
  float acc0 = 0.f, acc1 = 0.f;
  const float* base = inputs + ((size_t)b * 256 + s * 64) * 512;
  for (int nn = 0; nn < 64; ++nn) {
    const float a = a_sh[nn];
    const float* row = base + (size_t)nn * 512;
    acc0 += a * row[tid];
    acc1 += a * row[tid + 256];
  }
  tp[((size_t)s * 64 + b) * 512 + tid]       = acc0;
  tp[((size_t)s * 64 + b) * 512 + tid + 256] = acc1;
}

__global__ __launch_bounds__(256)
void tree_reduce(const float* __restrict__ tp, float* __restrict__ tre) {
  const int i = blockIdx.x * 256 + threadIdx.x;   // 32768
  tre[i] = tp[i] + tp[32768 + i] + tp[65536 + i] + tp[98304 + i];
}

// ---------- ctrl_h split-K ----------
__global__ __launch_bounds__(256)
void ctrl_gemm(const float* __restrict__ h0, const float* __restrict__ W_h,
               float* __restrict__ chp) {
  const int col = blockIdx.x * 256 + threadIdx.x;
  const int b   = blockIdx.y;
  const int z   = blockIdx.z;
  __shared__ float hsh[128];
  if (threadIdx.x < 128) hsh[threadIdx.x] = h0[b * 512 + z * 128 + threadIdx.x];
  __syncthreads();
  const float* Wp = W_h + (size_t)(512 + z * 128) * 512 + col;
  float s = 0.f;
#pragma unroll 8
  for (int k = 0; k < 128; ++k) s += hsh[k] * Wp[(size_t)k * 512];
  chp[((size_t)z * 64 + b) * 512 + col] = s;
}

__global__ __launch_bounds__(256)
void ctrl_reduce(const float* __restrict__ chp, float* __restrict__ ch) {
  const int i = blockIdx.x * 256 + threadIdx.x;
  ch[i] = chp[i] + chp[32768 + i] + chp[65536 + i] + chp[98304 + i];
}

// ---------- LSTM split-K ----------
__global__ __launch_bounds__(256)
void lstm_gemm_splitk(const float* __restrict__ tre, const float* __restrict__ h0,
                      const float* __restrict__ kern, const float* __restrict__ rec,
                      float* __restrict__ Zp) {
  const int tid = threadIdx.x;
  const int col = blockIdx.x * 256 + tid;
  const int b0 = blockIdx.y * 4;
  const int z = blockIdx.z;
  const float* X = (z < 4) ? tre : h0;
  const float* W = (z < 4) ? (kern + (size_t)z * 128 * 2048)
                           : (rec + (size_t)(z - 4) * 128 * 2048);
  const int koff = (z & 3) * 128;
  __shared__ float xs[4][128];
  for (int i = tid; i < 512; i += 256) {
    int bb = i >> 7, k = i & 127;
    xs[bb][k] = X[(b0 + bb) * 512 + koff + k];
  }
  __syncthreads();
  float a0 = 0.f, a1 = 0.f, a2 = 0.f, a3 = 0.f;
#pragma unroll 8
  for (int k = 0; k < 128; ++k) {
    const float w = W[(size_t)k * 2048 + col];
    a0 += xs[0][k] * w;
    a1 += xs[1][k] * w;
    a2 += xs[2][k] * w;
    a3 += xs[3][k] * w;
  }
  Zp[((size_t)z * 64 + b0 + 0) * 2048 + col] = a0;
  Zp[((size_t)z * 64 + b0 + 1) * 2048 + col] = a1;
  Zp[((size_t)z * 64 + b0 + 2) * 2048 + col] = a2;
  Zp[((size_t)z * 64 + b0 + 3) * 2048 + col] = a3;
}

__global__ __launch_bounds__(256)
void lstm_combine(const float* __restrict__ Zp, const float* __restrict__ bias,
                  const float* __restrict__ c0,
                  float* __restrict__ out_h, float* __restrict__ out_c) {
  const int i = blockIdx.x * 256 + threadIdx.x;
  const int b = i >> 9, u = i & 511;
  float zi = bias[u], zf = bias[512 + u], zg = bias[1024 + u], zo = bias[1536 + u];
#pragma unroll
  for (int z = 0; z < 8; ++z) {
    const size_t base = ((size_t)z * 64 + b) * 2048;
    zi += Zp[base + u];
    zf += Zp[base + 512 + u];
    zg += Zp[base + 1024 + u];
    zo += Zp[base + 1536 + u];
  }
  const float c = sigmoidf_(zf) * c0[i] + sigmoidf_(zi) * tanhf(zg);
  out_h[i] = sigmoidf_(zo) * tanhf(c);
  out_c[i] = c;
}

extern "C" void kernel_launch(void* const* d_in, const int* in_sizes, int n_in,
                              void* d_out, int out_size, void* d_ws, size_t ws_size,
                              hipStream_t stream) {
  const float* inputs = (const float*)d_in[0];
  const float* h0     = (const float*)d_in[1];
  const float* c0     = (const float*)d_in[2];
  const float* W_t    = (const float*)d_in[3];
  const float* W_j    = (const float*)d_in[4];
  const float* W_s    = (const float*)d_in[5];
  const float* W_h    = (const float*)d_in[6];
  const float* W_T    = (const float*)d_in[7];
  const float* kern   = (const float*)d_in[8];
  const float* rec    = (const float*)d_in[9];
  const float* bias   = (const float*)d_in[10];
  float* out = (float*)d_out;

  char* p = (char*)d_ws;
  __hip_bfloat16* in_bf     = (__hip_bfloat16*)p; p += 16777216;   // 16384x512
  __hip_bfloat16* leaf_bf   = (__hip_bfloat16*)p; p += 16777216;   // 16384x512
  __hip_bfloat16* levels_bf = (__hip_bfloat16*)p; p += 16842752;   // 16320x512 + pad
  __hip_bfloat16* Wt_t      = (__hip_bfloat16*)p; p += 524288;
  __hip_bfloat16* Wt_j      = (__hip_bfloat16*)p; p += 1048576;
  __hip_bfloat16* Wt_h      = (__hip_bfloat16*)p; p += 524288;
  float* attn  = (float*)p; p += 65536;    // 64x256
  float* upd   = (float*)p; p += 65536;    // 64x256
  float* tre   = (float*)p; p += 131072;   // 64x512
  float* chp   = (float*)p; p += 524288;   // 4x64x512
  float* ch    = (float*)p; p += 131072;   // 64x512
  float* Zp    = (float*)p; p += 4194304;  // 8x64x2048
  float* sc    = (float*)p; p += 65536;    // 16320 node scores (+pad)
  float* ctrlT = (float*)p; p += 4096;     // 64
  float* tp    = (float*)p; p += 524288;   // 4x64x512 tree partials

  // prep (independent)
  cvt_bf16<<<8192, 256, 0, stream>>>(inputs, in_bf, 8388608);
  tconv_all<<<dim3(32, 16, 3), 256, 0, stream>>>(W_t, W_j, W_h, Wt_t, Wt_j, Wt_h);
  ctrl_gemm<<<dim3(2, 64, 4), 256, 0, stream>>>(h0, W_h, chp);
  ctrl_reduce<<<128, 256, 0, stream>>>(chp, ch);
  prep_ctrl<<<64, 256, 0, stream>>>(h0, W_T, ctrlT);

  // leaf embed
  mfma_gemm<0><<<dim3(4, 128), 256, 0, stream>>>(in_bf, Wt_t, 16384, 512,
                                                 leaf_bf, nullptr, nullptr, nullptr, nullptr, nullptr);
  // upd GEMV (needs leaf only)
  gemv512<<<4096, 256, 0, stream>>>(leaf_bf, W_T, ctrlT, upd, 1);

  // join levels 1..3 as tiled MFMA GEMMs
  const int lvl_off_h[9] = {0, 0, 4194304, 6291456, 7340032,
                            7864320, 8126464, 8257536, 8323072};
  const __hip_bfloat16* Aptr = leaf_bf;
  for (int l = 1; l <= 3; ++l) {
    const int M = 64 * (256 >> l);
    __hip_bfloat16* Cl = levels_bf + lvl_off_h[l];
    mfma_gemm<0><<<dim3(4, M / 128), 256, 0, stream>>>(Aptr, Wt_j, M, 1024,
                                                       Cl, nullptr, nullptr, nullptr, nullptr, nullptr);
    Aptr = Cl;
  }
  // levels 4..8: LDS-free wave-tile MFMA, 512 blocks each
  for (int l = 4; l <= 8; ++l) {
    join_level<<<dim3(8, 64), 256, 0, stream>>>(levels_bf + lvl_off_h[l - 1],
                                                levels_bf + lvl_off_h[l], Wt_j, 256 >> l);
  }

  // node scores GEMV over all 16320 level rows, then top-down attn
  gemv512<<<4080, 256, 0, stream>>>(levels_bf, W_s, nullptr, sc, 0);
  propagate<<<64, 256, 0, stream>>>(sc, h0, W_s, attn);

  // tree_out
  tree_part<<<dim3(4, 64), 256, 0, stream>>>(inputs, attn, tp);
  tree_reduce<<<128, 256, 0, stream>>>(tp, tre);

  // write stage -> leaf_h_new (fp32) at out[65536:]
  mfma_gemm<1><<<dim3(4, 128), 256, 0, stream>>>(leaf_bf, Wt_h, 16384, 512,
                                                 nullptr, out + 65536, ch, attn, upd, leaf_bf);
  // LSTM
  lstm_gemm_splitk<<<dim3(8, 16, 8), 256, 0, stream>>>(tre, h0, kern, rec, Zp);
  lstm_combine<<<128, 256, 0, stream>>>(Zp, bias, c0, out, out + 32768);
}

// Round 6
// 332.529 us; speedup vs baseline: 6.1290x; 1.0379x over previous
//
#include <hip/hip_runtime.h>
#include <hip/hip_bf16.h>
#include <cstdint>
#include <cstddef>

// B=64, N=256 leaves, E=D=U=512.
// Outputs: h_new[64*512], c_new[64*512], leaf_h_new[64*256*512] concat flat fp32.

__device__ __forceinline__ float sigmoidf_(float x) { return 1.0f / (1.0f + __expf(-x)); }

typedef __attribute__((ext_vector_type(8))) short bf16x8;
typedef __attribute__((ext_vector_type(4))) float f32x4;

__device__ __forceinline__ void load_lds16(const void* g, void* l) {
  __builtin_amdgcn_global_load_lds((const __attribute__((address_space(1))) void*)g,
                                   (__attribute__((address_space(3))) void*)l, 16, 0, 0);
}

// ---------- all three weight transposes in one launch ----------
__global__ __launch_bounds__(256)
void tconv_all(const float* __restrict__ W_t, const float* __restrict__ W_j,
               const float* __restrict__ W_h,
               __hip_bfloat16* __restrict__ Wt_t, __hip_bfloat16* __restrict__ Wt_j,
               __hip_bfloat16* __restrict__ Wt_h) {
  const int z = blockIdx.z;
  if (z != 1 && blockIdx.x >= 16) return;
  const int K = (z == 1) ? 1024 : 512;
  const float* W = (z == 0) ? W_t : ((z == 1) ? W_j : W_h);
  __hip_bfloat16* Wt = (z == 0) ? Wt_t : ((z == 1) ? Wt_j : Wt_h);
  __shared__ float sh[32][33];
  const int tx = threadIdx.x & 31, ty = threadIdx.x >> 5;
  const int k0 = blockIdx.x * 32, n0 = blockIdx.y * 32;
#pragma unroll
  for (int i = 0; i < 4; ++i)
    sh[ty + i * 8][tx] = W[(size_t)(k0 + ty + i * 8) * 512 + n0 + tx];
  __syncthreads();
#pragma unroll
  for (int i = 0; i < 4; ++i)
    Wt[(size_t)(n0 + ty + i * 8) * K + k0 + tx] = __float2bfloat16(sh[tx][ty + i * 8]);
}

// ---------- bf16 MFMA GEMM: C = epi(A[M,K] @ Bt^T), N=512 ----------
// AFP32: A is fp32, converted to bf16 during LDS staging (fused cvt).
// MODE 0: relu -> bf16 Cb.   MODE 1: write-stage epilogue -> fp32 Cf.
template<int MODE, bool AFP32>
__global__ __launch_bounds__(256)
void mfma_gemm(const __hip_bfloat16* __restrict__ A, const float* __restrict__ Af,
               const __hip_bfloat16* __restrict__ Bt, int M, int K,
               __hip_bfloat16* __restrict__ Cb, float* __restrict__ Cf,
               const float* __restrict__ ctrl_h, const float* __restrict__ attn,
               const float* __restrict__ upd, const __hip_bfloat16* __restrict__ leaf) {
  __shared__ __align__(16) __hip_bfloat16 Asm[128 * 32];
  __shared__ __align__(16) __hip_bfloat16 Bsm[128 * 32];
  const int tid = threadIdx.x;
  const int wave = tid >> 6, lane = tid & 63;
  const int bm = blockIdx.y * 128, bn = blockIdx.x * 128;
  const int wm = (wave >> 1) * 64, wn = (wave & 1) * 64;
  const int q = lane >> 4, lr = lane & 15;

  f32x4 acc[4][4] = {};

  const int c0 = wave * 128 + lane, c1 = c0 + 64;
  const size_t ga0 = (size_t)(bm + (c0 >> 2)) * K + (c0 & 3) * 8;
  const size_t ga1 = (size_t)(bm + (c1 >> 2)) * K + (c1 & 3) * 8;
  const size_t gb0 = (size_t)(bn + (c0 >> 2)) * K + (c0 & 3) * 8;
  const size_t gb1 = (size_t)(bn + (c1 >> 2)) * K + (c1 & 3) * 8;
  __hip_bfloat16* la0 = Asm + wave * 1024;
  __hip_bfloat16* la1 = Asm + wave * 1024 + 512;
  __hip_bfloat16* lb0 = Bsm + wave * 1024;
  __hip_bfloat16* lb1 = Bsm + wave * 1024 + 512;

  for (int k0v = 0; k0v < K; k0v += 32) {
    if (AFP32) {
      // stage A fp32 -> bf16: 128 rows x 32 k per tile, 4 float4 chunks/thread
#pragma unroll
      for (int it = 0; it < 4; ++it) {
        const int c = it * 256 + tid;          // 0..1023
        const int row = c >> 3, kc = c & 7;
        float4 v = *(const float4*)(Af + (size_t)(bm + row) * K + k0v + kc * 4);
        __hip_bfloat16 h[4] = {__float2bfloat16(v.x), __float2bfloat16(v.y),
                               __float2bfloat16(v.z), __float2bfloat16(v.w)};
        *(ushort4*)(Asm + row * 32 + kc * 4) = *(ushort4*)h;
      }
    } else {
      load_lds16(A + ga0 + k0v, la0);
      load_lds16(A + ga1 + k0v, la1);
    }
    load_lds16(Bt + gb0 + k0v, lb0);
    load_lds16(Bt + gb1 + k0v, lb1);
    __syncthreads();
    bf16x8 af[4], bfr[4];
#pragma unroll
    for (int mt = 0; mt < 4; ++mt)
      af[mt] = *(const bf16x8*)(Asm + (wm + mt * 16 + lr) * 32 + q * 8);
#pragma unroll
    for (int nt = 0; nt < 4; ++nt)
      bfr[nt] = *(const bf16x8*)(Bsm + (wn + nt * 16 + lr) * 32 + q * 8);
#pragma unroll
    for (int mt = 0; mt < 4; ++mt)
#pragma unroll
      for (int nt = 0; nt < 4; ++nt)
        acc[mt][nt] = __builtin_amdgcn_mfma_f32_16x16x32_bf16(af[mt], bfr[nt], acc[mt][nt], 0, 0, 0);
    __syncthreads();
  }

  // C/D layout: col = lane&15, row = (lane>>4)*4 + reg
  if (MODE == 0) {
#pragma unroll
    for (int mt = 0; mt < 4; ++mt) {
      const int rbase = bm + wm + mt * 16 + q * 4;
#pragma unroll
      for (int nt = 0; nt < 4; ++nt) {
        const int col = bn + wn + nt * 16 + lr;
#pragma unroll
        for (int r = 0; r < 4; ++r) {
          const int row = rbase + r;
          if (row < M)
            Cb[(size_t)row * 512 + col] = __float2bfloat16(fmaxf(acc[mt][nt][r], 0.f));
        }
      }
    }
  } else {
#pragma unroll
    for (int mt = 0; mt < 4; ++mt) {
      const int rbase = bm + wm + mt * 16 + q * 4;
#pragma unroll
      for (int r = 0; r < 4; ++r) {
        const int row = rbase + r;
        const float a = attn[row];
        const float u = upd[row];
        const int bidx = row >> 8;
#pragma unroll
        for (int nt = 0; nt < 4; ++nt) {
          const int col = bn + wn + nt * 16 + lr;
          const float cand = sigmoidf_(acc[mt][nt][r] + ctrl_h[(size_t)bidx * 512 + col]);
          const float lf = __bfloat162float(leaf[(size_t)row * 512 + col]);
          const float w = u * cand + (1.f - u) * lf;
          Cf[(size_t)row * 512 + col] = a * w + (1.f - a) * lf;
        }
      }
    }
  }
}

// ---------- tail join level: one 16x16 tile per wave, no LDS, no padding ----------
// Output row g (global across batches) consumes input rows 2g,2g+1 =
// 1024 contiguous bf16 at in + g*1024. M_total = 64*m_out, tiles = (M_total/16)*32,
// grid = tiles/4 = 32*m_out blocks.
__global__ __launch_bounds__(256)
void join_level(const __hip_bfloat16* __restrict__ in, __hip_bfloat16* __restrict__ outp,
                const __hip_bfloat16* __restrict__ Wt_j) {
  const int wave = threadIdx.x >> 6, lane = threadIdx.x & 63;
  const int q = lane >> 4, lr = lane & 15;
  const int tile = blockIdx.x * 4 + wave;
  const int mtile = tile >> 5, ntile = tile & 31;
  const __hip_bfloat16* ap = in + (size_t)(mtile * 16 + lr) * 1024 + q * 8;
  const __hip_bfloat16* bp = Wt_j + (size_t)(ntile * 16 + lr) * 1024 + q * 8;
  f32x4 acc = {0.f, 0.f, 0.f, 0.f};
#pragma unroll 8
  for (int k0 = 0; k0 < 1024; k0 += 32) {
    bf16x8 a  = *(const bf16x8*)(ap + k0);
    bf16x8 bb = *(const bf16x8*)(bp + k0);
    acc = __builtin_amdgcn_mfma_f32_16x16x32_bf16(a, bb, acc, 0, 0, 0);
  }
  const int col = ntile * 16 + lr;
  const int orow = mtile * 16 + q * 4;
#pragma unroll
  for (int r = 0; r < 4; ++r)
    outp[(size_t)(orow + r) * 512 + col] = __float2bfloat16(fmaxf(acc[r], 0.f));
}

// ---------- fused GEMV: upd (4096 blocks) + node scores (4080 blocks) ----------
__global__ __launch_bounds__(256)
void gemv_dual(const __hip_bfloat16* __restrict__ leaf,
               const __hip_bfloat16* __restrict__ levels,
               const float* __restrict__ W_T, const float* __restrict__ W_s,
               const float* __restrict__ ctrlT,
               float* __restrict__ upd, float* __restrict__ sc) {
  const int wave = threadIdx.x >> 6, lane = threadIdx.x & 63;
  const int bid = blockIdx.x;
  const bool is_upd = bid < 4096;
  const int row = (is_upd ? bid : (bid - 4096)) * 4 + wave;
  const __hip_bfloat16* X = is_upd ? leaf : levels;
  const float* w = is_upd ? W_T : W_s;
  union { bf16x8 v; __hip_bfloat16 e[8]; } u;
  u.v = *(const bf16x8*)(X + (size_t)row * 512 + lane * 8);
  const float* wp = w + lane * 8;
  float p = 0.f;
#pragma unroll
  for (int j = 0; j < 8; ++j) p += __bfloat162float(u.e[j]) * wp[j];
#pragma unroll
  for (int off = 32; off > 0; off >>= 1) p += __shfl_down(p, off);
  if (lane == 0) {
    if (is_upd) upd[row] = sigmoidf_(p + ctrlT[row >> 8]);
    else        sc[row] = p;
  }
}

// ---------- ctrl_T[b] = h0[b,:].W_T[512:] ----------
__global__ __launch_bounds__(256)
void prep_ctrl(const float* __restrict__ h0, const float* __restrict__ W_T,
               float* __restrict__ ctrlT) {
  const int b = blockIdx.x, tid = threadIdx.x;
  __shared__ float part[256];
  float p = 0.f;
  for (int i = tid; i < 512; i += 256) p += h0[b * 512 + i] * W_T[512 + i];
  part[tid] = p; __syncthreads();
  for (int s = 128; s > 0; s >>= 1) { if (tid < s) part[tid] += part[tid + s]; __syncthreads(); }
  if (tid == 0) ctrlT[b] = part[0];
}

// ---------- top-down attention from precomputed node scores ----------
__global__ __launch_bounds__(256)
void propagate(const float* __restrict__ sc, const float* __restrict__ h0,
               const float* __restrict__ W_s, float* __restrict__ attn_out) {
  const int b = blockIdx.x, tid = threadIdx.x;
  __shared__ float part[256], attn_sh[256], newattn[256];
  __shared__ float scs;
  float p = 0.f;
  for (int i = tid; i < 512; i += 256) p += h0[b * 512 + i] * W_s[512 + i];
  part[tid] = p; __syncthreads();
  for (int s = 128; s > 0; s >>= 1) { if (tid < s) part[tid] += part[tid + s]; __syncthreads(); }
  if (tid == 0) { scs = part[0]; attn_sh[0] = 1.f; }
  __syncthreads();
  const int row_off[9] = {0, 0, 8192, 12288, 14336, 15360, 15872, 16128, 16256};
#pragma unroll
  for (int l = 8; l >= 1; --l) {
    const int m = 256 >> l;
    if (tid < m) {
      const float mr = sigmoidf_(sc[row_off[l] + b * m + tid] + scs);
      const float a = attn_sh[tid];
      newattn[2 * tid]     = a * (1.f - mr);
      newattn[2 * tid + 1] = a * mr;
    }
    __syncthreads();
    if (tid < 2 * m) attn_sh[tid] = newattn[tid];
    __syncthreads();
  }
  attn_out[b * 256 + tid] = attn_sh[tid];
}

// ---------- tree_out partials over (n-slice, batch) ----------
__global__ __launch_bounds__(256)
void tree_part(const float* __restrict__ inputs, const float* __restrict__ attn,
               float* __restrict__ tp) {
  const int s = blockIdx.x, b = blockIdx.y;
  const int tid = threadIdx.x;
  __shared__ float a_sh[64];
  if (tid < 64) a_sh[tid] = attn[b * 256 + s * 64 + tid];
  __syncthreads();
  float acc0 = 0.f, acc1 = 0.f;
  const float* base = inputs + ((size_t)b * 256 + s * 64) * 512;
  for (int nn = 0; nn < 64; ++nn) {
    const float a = a_sh[nn];
    const float* row = base + (size_t)nn * 512;
    acc0 += a * row[tid];
    acc1 += a * row[tid + 256];
  }
  tp[((size_t)s * 64 + b) * 512 + tid]       = acc0;
  tp[((size_t)s * 64 + b) * 512 + tid + 256] = acc1;
}

__global__ __launch_bounds__(256)
void tree_reduce(const float* __restrict__ tp, float* __restrict__ tre) {
  const int i = blockIdx.x * 256 + threadIdx.x;   // 32768
  tre[i] = tp[i] + tp[32768 + i] + tp[65536 + i] + tp[98304 + i];
}

// ---------- ctrl_h split-K ----------
__global__ __launch_bounds__(256)
void ctrl_gemm(const float* __restrict__ h0, const float* __restrict__ W_h,
               float* __restrict__ chp) {
  const int col = blockIdx.x * 256 + threadIdx.x;
  const int b   = blockIdx.y;
  const int z   = blockIdx.z;
  __shared__ float hsh[128];
  if (threadIdx.x < 128) hsh[threadIdx.x] = h0[b * 512 + z * 128 + threadIdx.x];
  __syncthreads();
  const float* Wp = W_h + (size_t)(512 + z * 128) * 512 + col;
  float s = 0.f;
#pragma unroll 8
  for (int k = 0; k < 128; ++k) s += hsh[k] * Wp[(size_t)k * 512];
  chp[((size_t)z * 64 + b) * 512 + col] = s;
}

__global__ __launch_bounds__(256)
void ctrl_reduce(const float* __restrict__ chp, float* __restrict__ ch) {
  const int i = blockIdx.x * 256 + threadIdx.x;
  ch[i] = chp[i] + chp[32768 + i] + chp[65536 + i] + chp[98304 + i];
}

// ---------- LSTM split-K ----------
__global__ __launch_bounds__(256)
void lstm_gemm_splitk(const float* __restrict__ tre, const float* __restrict__ h0,
                      const float* __restrict__ kern, const float* __restrict__ rec,
                      float* __restrict__ Zp) {
  const int tid = threadIdx.x;
  const int col = blockIdx.x * 256 + tid;
  const int b0 = blockIdx.y * 4;
  const int z = blockIdx.z;
  const float* X = (z < 4) ? tre : h0;
  const float* W = (z < 4) ? (kern + (size_t)z * 128 * 2048)
                           : (rec + (size_t)(z - 4) * 128 * 2048);
  const int koff = (z & 3) * 128;
  __shared__ float xs[4][128];
  for (int i = tid; i < 512; i += 256) {
    int bb = i >> 7, k = i & 127;
    xs[bb][k] = X[(b0 + bb) * 512 + koff + k];
  }
  __syncthreads();
  float a0 = 0.f, a1 = 0.f, a2 = 0.f, a3 = 0.f;
#pragma unroll 8
  for (int k = 0; k < 128; ++k) {
    const float w = W[(size_t)k * 2048 + col];
    a0 += xs[0][k] * w;
    a1 += xs[1][k] * w;
    a2 += xs[2][k] * w;
    a3 += xs[3][k] * w;
  }
  Zp[((size_t)z * 64 + b0 + 0) * 2048 + col] = a0;
  Zp[((size_t)z * 64 + b0 + 1) * 2048 + col] = a1;
  Zp[((size_t)z * 64 + b0 + 2) * 2048 + col] = a2;
  Zp[((size_t)z * 64 + b0 + 3) * 2048 + col] = a3;
}

__global__ __launch_bounds__(256)
void lstm_combine(const float* __restrict__ Zp, const float* __restrict__ bias,
                  const float* __restrict__ c0,
                  float* __restrict__ out_h, float* __restrict__ out_c) {
  const int i = blockIdx.x * 256 + threadIdx.x;
  const int b = i >> 9, u = i & 511;
  float zi = bias[u], zf = bias[512 + u], zg = bias[1024 + u], zo = bias[1536 + u];
#pragma unroll
  for (int z = 0; z < 8; ++z) {
    const size_t base = ((size_t)z * 64 + b) * 2048;
    zi += Zp[base + u];
    zf += Zp[base + 512 + u];
    zg += Zp[base + 1024 + u];
    zo += Zp[base + 1536 + u];
  }
  const float c = sigmoidf_(zf) * c0[i] + sigmoidf_(zi) * tanhf(zg);
  out_h[i] = sigmoidf_(zo) * tanhf(c);
  out_c[i] = c;
}

extern "C" void kernel_launch(void* const* d_in, const int* in_sizes, int n_in,
                              void* d_out, int out_size, void* d_ws, size_t ws_size,
                              hipStream_t stream) {
  const float* inputs = (const float*)d_in[0];
  const float* h0     = (const float*)d_in[1];
  const float* c0     = (const float*)d_in[2];
  const float* W_t    = (const float*)d_in[3];
  const float* W_j    = (const float*)d_in[4];
  const float* W_s    = (const float*)d_in[5];
  const float* W_h    = (const float*)d_in[6];
  const float* W_T    = (const float*)d_in[7];
  const float* kern   = (const float*)d_in[8];
  const float* rec    = (const float*)d_in[9];
  const float* bias   = (const float*)d_in[10];
  float* out = (float*)d_out;

  char* p = (char*)d_ws;
  __hip_bfloat16* leaf_bf   = (__hip_bfloat16*)p; p += 16777216;   // 16384x512
  __hip_bfloat16* levels_bf = (__hip_bfloat16*)p; p += 16842752;   // 16320x512 + pad
  __hip_bfloat16* Wt_t      = (__hip_bfloat16*)p; p += 524288;
  __hip_bfloat16* Wt_j      = (__hip_bfloat16*)p; p += 1048576;
  __hip_bfloat16* Wt_h      = (__hip_bfloat16*)p; p += 524288;
  float* attn  = (float*)p; p += 65536;    // 64x256
  float* upd   = (float*)p; p += 65536;    // 64x256
  float* tre   = (float*)p; p += 131072;   // 64x512
  float* chp   = (float*)p; p += 524288;   // 4x64x512
  float* ch    = (float*)p; p += 131072;   // 64x512
  float* Zp    = (float*)p; p += 4194304;  // 8x64x2048
  float* sc    = (float*)p; p += 65536;    // 16320 node scores (+pad)
  float* ctrlT = (float*)p; p += 4096;     // 64
  float* tp    = (float*)p; p += 524288;   // 4x64x512 tree partials

  // prep (independent)
  tconv_all<<<dim3(32, 16, 3), 256, 0, stream>>>(W_t, W_j, W_h, Wt_t, Wt_j, Wt_h);
  ctrl_gemm<<<dim3(2, 64, 4), 256, 0, stream>>>(h0, W_h, chp);
  ctrl_reduce<<<128, 256, 0, stream>>>(chp, ch);
  prep_ctrl<<<64, 256, 0, stream>>>(h0, W_T, ctrlT);

  // leaf embed with fused fp32->bf16 staging
  mfma_gemm<0, true><<<dim3(4, 128), 256, 0, stream>>>(
      nullptr, inputs, Wt_t, 16384, 512,
      leaf_bf, nullptr, nullptr, nullptr, nullptr, nullptr);

  // join levels 1..3 as tiled MFMA GEMMs
  const int lvl_off_h[9] = {0, 0, 4194304, 6291456, 7340032,
                            7864320, 8126464, 8257536, 8323072};
  const __hip_bfloat16* Aptr = leaf_bf;
  for (int l = 1; l <= 3; ++l) {
    const int M = 64 * (256 >> l);
    __hip_bfloat16* Cl = levels_bf + lvl_off_h[l];
    mfma_gemm<0, false><<<dim3(4, M / 128), 256, 0, stream>>>(
        Aptr, nullptr, Wt_j, M, 1024,
        Cl, nullptr, nullptr, nullptr, nullptr, nullptr);
    Aptr = Cl;
  }
  // levels 4..8: LDS-free wave-tile MFMA, exact tiling (32*m_out blocks)
  for (int l = 4; l <= 8; ++l) {
    const int m_out = 256 >> l;
    join_level<<<32 * m_out, 256, 0, stream>>>(levels_bf + lvl_off_h[l - 1],
                                               levels_bf + lvl_off_h[l], Wt_j);
  }

  // fused upd + node-score GEMVs, then top-down attn
  gemv_dual<<<8176, 256, 0, stream>>>(leaf_bf, levels_bf, W_T, W_s, ctrlT, upd, sc);
  propagate<<<64, 256, 0, stream>>>(sc, h0, W_s, attn);

  // tree_out
  tree_part<<<dim3(4, 64), 256, 0, stream>>>(inputs, attn, tp);
  tree_reduce<<<128, 256, 0, stream>>>(tp, tre);

  // write stage -> leaf_h_new (fp32) at out[65536:]
  mfma_gemm<1, false><<<dim3(4, 128), 256, 0, stream>>>(
      leaf_bf, nullptr, Wt_h, 16384, 512,
      nullptr, out + 65536, ch, attn, upd, leaf_bf);
  // LSTM
  lstm_gemm_splitk<<<dim3(8, 16, 8), 256, 0, stream>>>(tre, h0, kern, rec, Zp);
  lstm_combine<<<128, 256, 0, stream>>>(Zp, bias, c0, out, out + 32768);
}